// Round 1
// baseline (3153.760 us; speedup 1.0000x reference)
//
#include <hip/hip_runtime.h>
#include <hip/hip_bf16.h>

#define TOKENS 4096   // N*S = 2*2048
#define EMB    1024
#define SEQ    2048
#define NHEAD  16
#define HDIM   64
#define FFN_D  4096

// ---------------------------------------------------------------------------
// K1: per-head-dim shared QKV projection.
// q[t, h*64+e] = sum_d x[t, h*64+d] * Wq[e][d]   (same for k, v)
// ---------------------------------------------------------------------------
__global__ __launch_bounds__(256) void qkv_kernel(
    const float* __restrict__ x,
    const float* __restrict__ Wq, const float* __restrict__ Wk,
    const float* __restrict__ Wv,
    float* __restrict__ q, float* __restrict__ k, float* __restrict__ v) {
  __shared__ float WqT[64][65], WkT[64][65], WvT[64][65];
  __shared__ float xs[1024];
  const int tid = threadIdx.x;
  // stage transposed weights: WT[d][e] = W[e*64+d]
  #pragma unroll
  for (int r = 0; r < 16; r++) {
    int idx = tid + 256 * r;        // idx = e*64 + d
    int e = idx >> 6, d = idx & 63;
    WqT[d][e] = Wq[idx];
    WkT[d][e] = Wk[idx];
    WvT[d][e] = Wv[idx];
  }
  for (int tkn = blockIdx.x; tkn < TOKENS; tkn += gridDim.x) {
    __syncthreads();
    #pragma unroll
    for (int j = 0; j < 4; j++)
      xs[tid + 256 * j] = x[(size_t)tkn * EMB + tid + 256 * j];
    __syncthreads();
    #pragma unroll
    for (int j = 0; j < 4; j++) {
      int ef = tid + 256 * j;
      int h = ef >> 6, ed = ef & 63;
      float aq = 0.f, ak = 0.f, av = 0.f;
      #pragma unroll
      for (int d = 0; d < 64; d++) {
        float xv = xs[h * 64 + d];   // broadcast within wave (uniform h)
        aq += xv * WqT[d][ed];
        ak += xv * WkT[d][ed];
        av += xv * WvT[d][ed];
      }
      size_t o = (size_t)tkn * EMB + ef;
      q[o] = aq; k[o] = ak; v[o] = av;
    }
  }
}

// ---------------------------------------------------------------------------
// K2: flash attention. Block = 4 waves, 16 q-rows of one (n,h).
// energy scale = 1/sqrt(EMB) = 1/32.
// ---------------------------------------------------------------------------
__global__ __launch_bounds__(256) void attn_kernel(
    const float* __restrict__ q, const float* __restrict__ k,
    const float* __restrict__ v, float* __restrict__ ctx) {
  __shared__ float Kt[64][65];      // Kt[d][j] transposed key tile
  __shared__ float Vs[64][64];      // Vs[j][d]
  __shared__ float qrow[16][64];
  __shared__ float pbuf[4][64];
  const int tid = threadIdx.x;
  const int wave = tid >> 6, lane = tid & 63;
  const int b = blockIdx.x;
  const int nh = b >> 7;            // SEQ/16 = 128 q-chunks per (n,h)
  const int qc = b & 127;
  const int n = nh >> 4, h = nh & 15;
  const int q0 = qc * 16;
  const size_t base = (size_t)n * SEQ * EMB + h * 64;

  #pragma unroll
  for (int r = 0; r < 4; r++) {
    int idx = tid + 256 * r;
    int row = idx >> 6, d = idx & 63;
    qrow[row][d] = q[base + (size_t)(q0 + row) * EMB + d];
  }

  float m[4], l[4], o[4];
  #pragma unroll
  for (int r = 0; r < 4; r++) { m[r] = -1e30f; l[r] = 0.f; o[r] = 0.f; }

  for (int j0 = 0; j0 < SEQ; j0 += 64) {
    __syncthreads();
    #pragma unroll
    for (int r = 0; r < 16; r++) {
      int idx = tid + 256 * r;
      int jk = idx >> 6, d = idx & 63;
      size_t g = base + (size_t)(j0 + jk) * EMB + d;
      Kt[d][jk] = k[g];
      Vs[jk][d] = v[g];
    }
    __syncthreads();
    #pragma unroll 1
    for (int rr = 0; rr < 4; rr++) {
      const int qi = wave * 4 + rr;
      float a0 = 0.f, a1 = 0.f;
      #pragma unroll
      for (int d = 0; d < 64; d += 2) {
        a0 += qrow[qi][d]     * Kt[d][lane];
        a1 += qrow[qi][d + 1] * Kt[d + 1][lane];
      }
      float s = (a0 + a1) * 0.03125f;
      float tm = s;
      #pragma unroll
      for (int off = 32; off >= 1; off >>= 1)
        tm = fmaxf(tm, __shfl_xor(tm, off, 64));
      float mn = fmaxf(m[rr], tm);
      float scale = __expf(m[rr] - mn);
      float p = __expf(s - mn);
      float ps = p;
      #pragma unroll
      for (int off = 32; off >= 1; off >>= 1)
        ps += __shfl_xor(ps, off, 64);
      l[rr] = l[rr] * scale + ps;
      m[rr] = mn;
      pbuf[wave][lane] = p;          // wave-local LDS (in-order DS pipe)
      float c0 = 0.f, c1 = 0.f;
      #pragma unroll
      for (int jj = 0; jj < 64; jj += 2) {
        c0 += pbuf[wave][jj]     * Vs[jj][lane];
        c1 += pbuf[wave][jj + 1] * Vs[jj + 1][lane];
      }
      o[rr] = o[rr] * scale + (c0 + c1);
    }
  }
  #pragma unroll
  for (int rr = 0; rr < 4; rr++)
    ctx[base + (size_t)(q0 + wave * 4 + rr) * EMB + lane] = o[rr] / l[rr];
}

// ---------------------------------------------------------------------------
// K3: tiled GEMM  out[t][c] = sum_i X[t][i] * W[c][i] + bias[c] (+resid)(+relu)
// 64x64 tile, Kt=32, 256 threads, 4x4 micro-tile per thread.
// ---------------------------------------------------------------------------
template <int K, bool RELU, bool RES>
__global__ __launch_bounds__(256) void gemm_kernel(
    const float* __restrict__ X, const float* __restrict__ W,
    const float* __restrict__ bias, const float* __restrict__ resid,
    float* __restrict__ out, int Nout) {
  __shared__ float Xs[32][68];   // Xs[i][r] (transposed), stride 68 -> 16B-aligned rows
  __shared__ float Ws[32][68];   // Ws[i][c]
  const int tid = threadIdx.x;
  const int tx = tid & 15, ty = tid >> 4;
  const int c0 = blockIdx.x * 64;
  const int t0 = blockIdx.y * 64;
  const int r_ = tid >> 5;       // 0..7
  const int kk = tid & 31;       // 0..31
  float acc[4][4] = {};

  for (int i0 = 0; i0 < K; i0 += 32) {
    __syncthreads();
    #pragma unroll
    for (int rep = 0; rep < 8; rep++) {
      int row = rep * 8 + r_;
      Xs[kk][row] = X[(size_t)(t0 + row) * K + i0 + kk];
      Ws[kk][row] = W[(size_t)(c0 + row) * K + i0 + kk];
    }
    __syncthreads();
    #pragma unroll
    for (int i = 0; i < 32; i++) {
      float4 xa = *reinterpret_cast<const float4*>(&Xs[i][ty * 4]);
      float4 wb = *reinterpret_cast<const float4*>(&Ws[i][tx * 4]);
      float xr[4] = {xa.x, xa.y, xa.z, xa.w};
      float wr[4] = {wb.x, wb.y, wb.z, wb.w};
      #pragma unroll
      for (int a = 0; a < 4; a++)
        #pragma unroll
        for (int c = 0; c < 4; c++)
          acc[a][c] += xr[a] * wr[c];
    }
  }

  #pragma unroll
  for (int a = 0; a < 4; a++) {
    int row = t0 + ty * 4 + a;
    int col = c0 + tx * 4;
    float4 bv = *reinterpret_cast<const float4*>(&bias[col]);
    float4 res;
    res.x = acc[a][0] + bv.x;
    res.y = acc[a][1] + bv.y;
    res.z = acc[a][2] + bv.z;
    res.w = acc[a][3] + bv.w;
    if constexpr (RES) {
      float4 rv = *reinterpret_cast<const float4*>(&resid[(size_t)row * Nout + col]);
      res.x += rv.x; res.y += rv.y; res.z += rv.z; res.w += rv.w;
    }
    if constexpr (RELU) {
      res.x = fmaxf(res.x, 0.f); res.y = fmaxf(res.y, 0.f);
      res.z = fmaxf(res.z, 0.f); res.w = fmaxf(res.w, 0.f);
    }
    *reinterpret_cast<float4*>(&out[(size_t)row * Nout + col]) = res;
  }
}

// ---------------------------------------------------------------------------
// K4: in-place LayerNorm over rows of width 1024.
// ---------------------------------------------------------------------------
__global__ __launch_bounds__(256) void ln_kernel(
    float* __restrict__ io, const float* __restrict__ g,
    const float* __restrict__ b) {
  __shared__ float sw[4], ssw[4];
  const int tid = threadIdx.x;
  const int row = blockIdx.x;
  const int wave = tid >> 6, lane = tid & 63;
  float vals[4];
  float s = 0.f, ss = 0.f;
  #pragma unroll
  for (int j = 0; j < 4; j++) {
    float vv = io[(size_t)row * EMB + tid + 256 * j];
    vals[j] = vv; s += vv; ss += vv * vv;
  }
  #pragma unroll
  for (int off = 32; off >= 1; off >>= 1) {
    s += __shfl_xor(s, off, 64);
    ss += __shfl_xor(ss, off, 64);
  }
  if (lane == 0) { sw[wave] = s; ssw[wave] = ss; }
  __syncthreads();
  float st = sw[0] + sw[1] + sw[2] + sw[3];
  float sst = ssw[0] + ssw[1] + ssw[2] + ssw[3];
  float mu = st * (1.f / EMB);
  float var = sst * (1.f / EMB) - mu * mu;
  float rs = rsqrtf(var + 1e-5f);
  #pragma unroll
  for (int j = 0; j < 4; j++) {
    int e = tid + 256 * j;
    io[(size_t)row * EMB + e] = (vals[j] - mu) * rs * g[e] + b[e];
  }
}

// ---------------------------------------------------------------------------
extern "C" void kernel_launch(void* const* d_in, const int* in_sizes, int n_in,
                              void* d_out, int out_size, void* d_ws, size_t ws_size,
                              hipStream_t stream) {
  const float* x    = (const float*)d_in[0];
  const float* Wq   = (const float*)d_in[1];
  const float* Wk   = (const float*)d_in[2];
  const float* Wv   = (const float*)d_in[3];
  const float* Wo   = (const float*)d_in[4];
  const float* bo   = (const float*)d_in[5];
  const float* ln1g = (const float*)d_in[6];
  const float* ln1b = (const float*)d_in[7];
  const float* ln2g = (const float*)d_in[8];
  const float* ln2b = (const float*)d_in[9];
  const float* W1   = (const float*)d_in[10];
  const float* b1   = (const float*)d_in[11];
  const float* W2   = (const float*)d_in[12];
  const float* b2   = (const float*)d_in[13];
  float* out = (float*)d_out;

  const size_t TE = (size_t)TOKENS * EMB;
  float* q   = (float*)d_ws;
  float* k   = q + TE;
  float* v   = k + TE;
  float* ctx = v + TE;
  float* x1  = ctx + TE;
  float* ff1 = q;               // reuse q..ctx region (4*TE == TOKENS*FFN_D)

  qkv_kernel<<<1024, 256, 0, stream>>>(x, Wq, Wk, Wv, q, k, v);
  attn_kernel<<<4096, 256, 0, stream>>>(q, k, v, ctx);
  // attn_out = ctx @ Wo.T + bo + x  -> x1 (pre-LN), then LN in place
  gemm_kernel<1024, false, true><<<dim3(EMB / 64, TOKENS / 64), 256, 0, stream>>>(
      ctx, Wo, bo, x, x1, EMB);
  ln_kernel<<<TOKENS, 256, 0, stream>>>(x1, ln1g, ln1b);
  // ff1 = relu(x1 @ W1.T + b1)
  gemm_kernel<1024, true, false><<<dim3(FFN_D / 64, TOKENS / 64), 256, 0, stream>>>(
      x1, W1, b1, nullptr, ff1, FFN_D);
  // out = ff1 @ W2.T + b2 + x1, then LN in place
  gemm_kernel<4096, false, true><<<dim3(EMB / 64, TOKENS / 64), 256, 0, stream>>>(
      ff1, W2, b2, x1, out, EMB);
  ln_kernel<<<TOKENS, 256, 0, stream>>>(out, ln2g, ln2b);
}

// Round 2
// 1413.596 us; speedup vs baseline: 2.2310x; 2.2310x over previous
//
#include <hip/hip_runtime.h>
#include <hip/hip_bf16.h>

#define TOKENS 4096   // N*S = 2*2048
#define EMB    1024
#define SEQ    2048
#define NHEAD  16
#define HDIM   64
#define FFN_D  4096

typedef __attribute__((ext_vector_type(8))) short bf16x8;
typedef __attribute__((ext_vector_type(4))) float f32x4;

static __device__ inline unsigned short f2bf(float f) {
  unsigned int u = __float_as_uint(f);
  unsigned int r = (u + 0x7fffu + ((u >> 16) & 1u)) >> 16;  // RNE
  return (unsigned short)r;
}

// ---------------------------------------------------------------------------
// K1: per-head-dim shared QKV projection -> bf16 outputs.
// q[t, h*64+e] = sum_d x[t, h*64+d] * Wq[e][d]
// ---------------------------------------------------------------------------
__global__ __launch_bounds__(256) void qkv_kernel(
    const float* __restrict__ x,
    const float* __restrict__ Wq, const float* __restrict__ Wk,
    const float* __restrict__ Wv,
    unsigned short* __restrict__ q, unsigned short* __restrict__ k,
    unsigned short* __restrict__ v) {
  __shared__ float WqT[64][65], WkT[64][65], WvT[64][65];
  __shared__ float xs[1024];
  const int tid = threadIdx.x;
  #pragma unroll
  for (int r = 0; r < 16; r++) {
    int idx = tid + 256 * r;        // idx = e*64 + d
    int e = idx >> 6, d = idx & 63;
    WqT[d][e] = Wq[idx];
    WkT[d][e] = Wk[idx];
    WvT[d][e] = Wv[idx];
  }
  for (int tkn = blockIdx.x; tkn < TOKENS; tkn += gridDim.x) {
    __syncthreads();
    #pragma unroll
    for (int j = 0; j < 4; j++)
      xs[tid + 256 * j] = x[(size_t)tkn * EMB + tid + 256 * j];
    __syncthreads();
    #pragma unroll
    for (int j = 0; j < 4; j++) {
      int ef = tid + 256 * j;
      int h = ef >> 6, ed = ef & 63;
      float aq = 0.f, ak = 0.f, av = 0.f;
      #pragma unroll
      for (int d = 0; d < 64; d++) {
        float xv = xs[h * 64 + d];
        aq += xv * WqT[d][ed];
        ak += xv * WkT[d][ed];
        av += xv * WvT[d][ed];
      }
      size_t o = (size_t)tkn * EMB + ef;
      q[o] = f2bf(aq); k[o] = f2bf(ak); v[o] = f2bf(av);
    }
  }
}

// ---------------------------------------------------------------------------
// K2: MFMA flash attention (bf16 in, f32 out).
// Block: 4 waves; each wave owns 16 q-rows; Q-tile 64, K-tile 64.
// Layout assumptions (16x16x32 bf16):
//   A-frag: lane holds A[lane%16][32*kh + 8*(lane/16) + j], j=0..7 (b128)
//   B-frag: lane holds B[32*kh + 8*(lane/16) + j][lane%16]
//   C/D  : lane holds D[(lane/16)*4 + r][lane%16]  (HW-verified)
// k-permutation errors cancel since A and B use the identical k-map.
// ---------------------------------------------------------------------------
__global__ __launch_bounds__(256) void attn_mfma(
    const unsigned short* __restrict__ q, const unsigned short* __restrict__ k,
    const unsigned short* __restrict__ v, float* __restrict__ ctx) {
  __shared__ unsigned short Ks[64][72];     // [key][dim]
  __shared__ unsigned short Vt[64][72];     // [dim][key]
  __shared__ unsigned short Ps[4][16][72];  // per-wave [qrow][key]
  const int tid = threadIdx.x;
  const int wave = tid >> 6, lane = tid & 63;
  const int lg = lane >> 4, lc = lane & 15;
  const int b = blockIdx.x;
  const int qt = b & 31, nh = b >> 5;       // 32 q-tiles per (n,h)
  const int n = nh >> 4, h = nh & 15;
  const size_t base = (size_t)n * SEQ * EMB + h * 64;
  const int q0 = qt * 64 + wave * 16;

  // Q fragments stay in registers for the whole block
  bf16x8 qa[2];
  qa[0] = *reinterpret_cast<const bf16x8*>(&q[base + (size_t)(q0 + lc) * EMB + lg * 8]);
  qa[1] = *reinterpret_cast<const bf16x8*>(&q[base + (size_t)(q0 + lc) * EMB + 32 + lg * 8]);

  f32x4 of[4];
  float m[4], l[4];
  #pragma unroll
  for (int nn = 0; nn < 4; nn++) {
    f32x4 z = {0.f, 0.f, 0.f, 0.f};
    of[nn] = z;
  }
  #pragma unroll
  for (int r = 0; r < 4; r++) { m[r] = -1e30f; l[r] = 0.f; }

  for (int j0 = 0; j0 < SEQ; j0 += 64) {
    __syncthreads();
    // stage K tile: vectorized 16B copies
    #pragma unroll
    for (int it = 0; it < 2; it++) {
      int e8 = it * 256 + tid;
      int key = e8 >> 3, d8 = e8 & 7;
      *reinterpret_cast<bf16x8*>(&Ks[key][d8 * 8]) =
          *reinterpret_cast<const bf16x8*>(&k[base + (size_t)(j0 + key) * EMB + d8 * 8]);
    }
    // stage V transposed
    #pragma unroll
    for (int it = 0; it < 8; it++) {
      int pr = it * 256 + tid;
      int key = pr >> 5, dp = pr & 31;
      unsigned int rv = *reinterpret_cast<const unsigned int*>(
          &v[base + (size_t)(j0 + key) * EMB + dp * 2]);
      Vt[dp * 2][key]     = (unsigned short)(rv & 0xffffu);
      Vt[dp * 2 + 1][key] = (unsigned short)(rv >> 16);
    }
    __syncthreads();

    // S = Q K^T / 32
    f32x4 sf[4];
    #pragma unroll
    for (int nn = 0; nn < 4; nn++) {
      bf16x8 kb0 = *reinterpret_cast<const bf16x8*>(&Ks[nn * 16 + lc][lg * 8]);
      bf16x8 kb1 = *reinterpret_cast<const bf16x8*>(&Ks[nn * 16 + lc][32 + lg * 8]);
      f32x4 z = {0.f, 0.f, 0.f, 0.f};
      z = __builtin_amdgcn_mfma_f32_16x16x32_bf16(qa[0], kb0, z, 0, 0, 0);
      z = __builtin_amdgcn_mfma_f32_16x16x32_bf16(qa[1], kb1, z, 0, 0, 0);
      #pragma unroll
      for (int r = 0; r < 4; r++) sf[nn][r] = z[r] * 0.03125f;
    }

    // online softmax (rows live across lc-lanes; reduce in-lane over nn, then xor 1,2,4,8)
    #pragma unroll
    for (int r = 0; r < 4; r++) {
      float t = fmaxf(fmaxf(sf[0][r], sf[1][r]), fmaxf(sf[2][r], sf[3][r]));
      t = fmaxf(t, __shfl_xor(t, 1));
      t = fmaxf(t, __shfl_xor(t, 2));
      t = fmaxf(t, __shfl_xor(t, 4));
      t = fmaxf(t, __shfl_xor(t, 8));
      float mn = fmaxf(m[r], t);
      float sc = __expf(m[r] - mn);
      m[r] = mn;
      float ps = 0.f;
      #pragma unroll
      for (int nn = 0; nn < 4; nn++) {
        float p = __expf(sf[nn][r] - mn);
        sf[nn][r] = p;
        ps += p;
      }
      ps += __shfl_xor(ps, 1);
      ps += __shfl_xor(ps, 2);
      ps += __shfl_xor(ps, 4);
      ps += __shfl_xor(ps, 8);
      l[r] = l[r] * sc + ps;
      #pragma unroll
      for (int nn = 0; nn < 4; nn++) {
        of[nn][r] *= sc;
        Ps[wave][lg * 4 + r][nn * 16 + lc] = f2bf(sf[nn][r]);
      }
    }

    // O += P V   (P via wave-private LDS round-trip; same-wave DS ordering)
    bf16x8 pa0 = *reinterpret_cast<const bf16x8*>(&Ps[wave][lc][lg * 8]);
    bf16x8 pa1 = *reinterpret_cast<const bf16x8*>(&Ps[wave][lc][32 + lg * 8]);
    #pragma unroll
    for (int nn = 0; nn < 4; nn++) {
      bf16x8 vb0 = *reinterpret_cast<const bf16x8*>(&Vt[nn * 16 + lc][lg * 8]);
      bf16x8 vb1 = *reinterpret_cast<const bf16x8*>(&Vt[nn * 16 + lc][32 + lg * 8]);
      of[nn] = __builtin_amdgcn_mfma_f32_16x16x32_bf16(pa0, vb0, of[nn], 0, 0, 0);
      of[nn] = __builtin_amdgcn_mfma_f32_16x16x32_bf16(pa1, vb1, of[nn], 0, 0, 0);
    }
  }

  #pragma unroll
  for (int r = 0; r < 4; r++) {
    float rl = 1.0f / l[r];
    #pragma unroll
    for (int nn = 0; nn < 4; nn++)
      ctx[base + (size_t)(q0 + lg * 4 + r) * EMB + nn * 16 + lc] = of[nn][r] * rl;
  }
}

// ---------------------------------------------------------------------------
// K3: tiled f32 GEMM  out[t][c] = sum_i X[t][i]*W[c][i] + bias[c] (+res)(+relu)
// ---------------------------------------------------------------------------
template <int K, bool RELU, bool RES>
__global__ __launch_bounds__(256) void gemm_kernel(
    const float* __restrict__ X, const float* __restrict__ W,
    const float* __restrict__ bias, const float* __restrict__ resid,
    float* __restrict__ out, int Nout) {
  __shared__ float Xs[32][68];
  __shared__ float Ws[32][68];
  const int tid = threadIdx.x;
  const int tx = tid & 15, ty = tid >> 4;
  const int c0 = blockIdx.x * 64;
  const int t0 = blockIdx.y * 64;
  const int r_ = tid >> 5;
  const int kk = tid & 31;
  float acc[4][4] = {};

  for (int i0 = 0; i0 < K; i0 += 32) {
    __syncthreads();
    #pragma unroll
    for (int rep = 0; rep < 8; rep++) {
      int row = rep * 8 + r_;
      Xs[kk][row] = X[(size_t)(t0 + row) * K + i0 + kk];
      Ws[kk][row] = W[(size_t)(c0 + row) * K + i0 + kk];
    }
    __syncthreads();
    #pragma unroll
    for (int i = 0; i < 32; i++) {
      float4 xa = *reinterpret_cast<const float4*>(&Xs[i][ty * 4]);
      float4 wb = *reinterpret_cast<const float4*>(&Ws[i][tx * 4]);
      float xr[4] = {xa.x, xa.y, xa.z, xa.w};
      float wr[4] = {wb.x, wb.y, wb.z, wb.w};
      #pragma unroll
      for (int a = 0; a < 4; a++)
        #pragma unroll
        for (int c = 0; c < 4; c++)
          acc[a][c] += xr[a] * wr[c];
    }
  }

  #pragma unroll
  for (int a = 0; a < 4; a++) {
    int row = t0 + ty * 4 + a;
    int col = c0 + tx * 4;
    float4 bv = *reinterpret_cast<const float4*>(&bias[col]);
    float4 res;
    res.x = acc[a][0] + bv.x;
    res.y = acc[a][1] + bv.y;
    res.z = acc[a][2] + bv.z;
    res.w = acc[a][3] + bv.w;
    if constexpr (RES) {
      float4 rv = *reinterpret_cast<const float4*>(&resid[(size_t)row * Nout + col]);
      res.x += rv.x; res.y += rv.y; res.z += rv.z; res.w += rv.w;
    }
    if constexpr (RELU) {
      res.x = fmaxf(res.x, 0.f); res.y = fmaxf(res.y, 0.f);
      res.z = fmaxf(res.z, 0.f); res.w = fmaxf(res.w, 0.f);
    }
    *reinterpret_cast<float4*>(&out[(size_t)row * Nout + col]) = res;
  }
}

// ---------------------------------------------------------------------------
// K4: in-place LayerNorm over rows of width 1024.
// ---------------------------------------------------------------------------
__global__ __launch_bounds__(256) void ln_kernel(
    float* __restrict__ io, const float* __restrict__ g,
    const float* __restrict__ b) {
  __shared__ float sw[4], ssw[4];
  const int tid = threadIdx.x;
  const int row = blockIdx.x;
  const int wave = tid >> 6, lane = tid & 63;
  float vals[4];
  float s = 0.f, ss = 0.f;
  #pragma unroll
  for (int j = 0; j < 4; j++) {
    float vv = io[(size_t)row * EMB + tid + 256 * j];
    vals[j] = vv; s += vv; ss += vv * vv;
  }
  #pragma unroll
  for (int off = 32; off >= 1; off >>= 1) {
    s += __shfl_xor(s, off, 64);
    ss += __shfl_xor(ss, off, 64);
  }
  if (lane == 0) { sw[wave] = s; ssw[wave] = ss; }
  __syncthreads();
  float st = sw[0] + sw[1] + sw[2] + sw[3];
  float sst = ssw[0] + ssw[1] + ssw[2] + ssw[3];
  float mu = st * (1.f / EMB);
  float var = sst * (1.f / EMB) - mu * mu;
  float rs = rsqrtf(var + 1e-5f);
  #pragma unroll
  for (int j = 0; j < 4; j++) {
    int e = tid + 256 * j;
    io[(size_t)row * EMB + e] = (vals[j] - mu) * rs * g[e] + b[e];
  }
}

// ---------------------------------------------------------------------------
extern "C" void kernel_launch(void* const* d_in, const int* in_sizes, int n_in,
                              void* d_out, int out_size, void* d_ws, size_t ws_size,
                              hipStream_t stream) {
  const float* x    = (const float*)d_in[0];
  const float* Wq   = (const float*)d_in[1];
  const float* Wk   = (const float*)d_in[2];
  const float* Wv   = (const float*)d_in[3];
  const float* Wo   = (const float*)d_in[4];
  const float* bo   = (const float*)d_in[5];
  const float* ln1g = (const float*)d_in[6];
  const float* ln1b = (const float*)d_in[7];
  const float* ln2g = (const float*)d_in[8];
  const float* ln2b = (const float*)d_in[9];
  const float* W1   = (const float*)d_in[10];
  const float* b1   = (const float*)d_in[11];
  const float* W2   = (const float*)d_in[12];
  const float* b2   = (const float*)d_in[13];
  float* out = (float*)d_out;

  const size_t TE = (size_t)TOKENS * EMB;
  // bf16 q/k/v: [0, 24MB); ctx f32: [24MB, 40.8MB)
  unsigned short* qb = (unsigned short*)d_ws;
  unsigned short* kb = qb + TE;
  unsigned short* vb = kb + TE;
  float* ctx = (float*)(vb + TE);
  // ff1 f32 [0, 64MB) reuses qb/kb/vb/ctx after they are dead
  float* ff1 = (float*)d_ws;
  // x1 f32 [64MB, 80.8MB) must survive until the last GEMM
  float* x1 = (float*)((char*)d_ws + (size_t)64 * 1024 * 1024);

  qkv_kernel<<<1024, 256, 0, stream>>>(x, Wq, Wk, Wv, qb, kb, vb);
  attn_mfma<<<1024, 256, 0, stream>>>(qb, kb, vb, ctx);
  // x1 = ctx @ Wo.T + bo + x, then LN in place
  gemm_kernel<1024, false, true><<<dim3(EMB / 64, TOKENS / 64), 256, 0, stream>>>(
      ctx, Wo, bo, x, x1, EMB);
  ln_kernel<<<TOKENS, 256, 0, stream>>>(x1, ln1g, ln1b);
  // ff1 = relu(x1 @ W1.T + b1)
  gemm_kernel<1024, true, false><<<dim3(FFN_D / 64, TOKENS / 64), 256, 0, stream>>>(
      x1, W1, b1, nullptr, ff1, FFN_D);
  // out = ff1 @ W2.T + b2 + x1, then LN in place
  gemm_kernel<4096, false, true><<<dim3(EMB / 64, TOKENS / 64), 256, 0, stream>>>(
      ff1, W2, b2, x1, out, EMB);
  ln_kernel<<<TOKENS, 256, 0, stream>>>(out, ln2g, ln2b);
}

// Round 3
// 438.162 us; speedup vs baseline: 7.1977x; 3.2262x over previous
//
#include <hip/hip_runtime.h>
#include <hip/hip_bf16.h>

#define TOKENS 4096   // N*S = 2*2048
#define EMB    1024
#define SEQ    2048
#define NHEAD  16
#define HDIM   64
#define FFN_D  4096

typedef __attribute__((ext_vector_type(8))) short bf16x8;
typedef __attribute__((ext_vector_type(4))) float f32x4;

static __device__ __forceinline__ unsigned short f2bf(float f) {
  unsigned int u = __float_as_uint(f);
  unsigned int r = (u + 0x7fffu + ((u >> 16) & 1u)) >> 16;  // RNE
  return (unsigned short)r;
}

// async global->LDS, 16B per lane; LDS dest = wave-uniform base + lane*16
static __device__ __forceinline__ void gload_lds16(const unsigned short* g,
                                                   unsigned short* l) {
  __builtin_amdgcn_global_load_lds(
      (const __attribute__((address_space(1))) void*)g,
      (__attribute__((address_space(3))) void*)l, 16, 0, 0);
}

// ---------------------------------------------------------------------------
// K0: f32 -> bf16 convert (weights), 8 elems/thread
// ---------------------------------------------------------------------------
__global__ __launch_bounds__(256) void cvt_kernel(
    const float* __restrict__ in, unsigned short* __restrict__ out, int n) {
  int i = (blockIdx.x * 256 + threadIdx.x) * 8;
  if (i >= n) return;
  float4 v0 = *reinterpret_cast<const float4*>(&in[i]);
  float4 v1 = *reinterpret_cast<const float4*>(&in[i + 4]);
  bf16x8 ov;
  ov[0] = (short)f2bf(v0.x); ov[1] = (short)f2bf(v0.y);
  ov[2] = (short)f2bf(v0.z); ov[3] = (short)f2bf(v0.w);
  ov[4] = (short)f2bf(v1.x); ov[5] = (short)f2bf(v1.y);
  ov[6] = (short)f2bf(v1.z); ov[7] = (short)f2bf(v1.w);
  *reinterpret_cast<bf16x8*>(&out[i]) = ov;
}

// ---------------------------------------------------------------------------
// K1: per-head-dim shared QKV projection -> bf16 outputs.
// ---------------------------------------------------------------------------
__global__ __launch_bounds__(256) void qkv_kernel(
    const float* __restrict__ x,
    const float* __restrict__ Wq, const float* __restrict__ Wk,
    const float* __restrict__ Wv,
    unsigned short* __restrict__ q, unsigned short* __restrict__ k,
    unsigned short* __restrict__ v) {
  __shared__ float WqT[64][65], WkT[64][65], WvT[64][65];
  __shared__ float xs[1024];
  const int tid = threadIdx.x;
  #pragma unroll
  for (int r = 0; r < 16; r++) {
    int idx = tid + 256 * r;        // idx = e*64 + d
    int e = idx >> 6, d = idx & 63;
    WqT[d][e] = Wq[idx];
    WkT[d][e] = Wk[idx];
    WvT[d][e] = Wv[idx];
  }
  for (int tkn = blockIdx.x; tkn < TOKENS; tkn += gridDim.x) {
    __syncthreads();
    #pragma unroll
    for (int j = 0; j < 4; j++)
      xs[tid + 256 * j] = x[(size_t)tkn * EMB + tid + 256 * j];
    __syncthreads();
    #pragma unroll
    for (int j = 0; j < 4; j++) {
      int ef = tid + 256 * j;
      int h = ef >> 6, ed = ef & 63;
      float aq = 0.f, ak = 0.f, av = 0.f;
      #pragma unroll
      for (int d = 0; d < 64; d++) {
        float xv = xs[h * 64 + d];
        aq += xv * WqT[d][ed];
        ak += xv * WkT[d][ed];
        av += xv * WvT[d][ed];
      }
      size_t o = (size_t)tkn * EMB + ef;
      q[o] = f2bf(aq); k[o] = f2bf(ak); v[o] = f2bf(av);
    }
  }
}

// ---------------------------------------------------------------------------
// K2: MFMA flash attention (bf16 in, bf16 ctx out).
// ---------------------------------------------------------------------------
__global__ __launch_bounds__(256) void attn_mfma(
    const unsigned short* __restrict__ q, const unsigned short* __restrict__ k,
    const unsigned short* __restrict__ v, unsigned short* __restrict__ ctx) {
  __shared__ unsigned short Ks[64][72];     // [key][dim]
  __shared__ unsigned short Vt[64][72];     // [dim][key]
  __shared__ unsigned short Ps[4][16][72];  // per-wave [qrow][key]
  const int tid = threadIdx.x;
  const int wave = tid >> 6, lane = tid & 63;
  const int lg = lane >> 4, lc = lane & 15;
  const int b = blockIdx.x;
  const int qt = b & 31, nh = b >> 5;
  const int n = nh >> 4, h = nh & 15;
  const size_t base = (size_t)n * SEQ * EMB + h * 64;
  const int q0 = qt * 64 + wave * 16;

  bf16x8 qa[2];
  qa[0] = *reinterpret_cast<const bf16x8*>(&q[base + (size_t)(q0 + lc) * EMB + lg * 8]);
  qa[1] = *reinterpret_cast<const bf16x8*>(&q[base + (size_t)(q0 + lc) * EMB + 32 + lg * 8]);

  f32x4 of[4];
  float m[4], l[4];
  #pragma unroll
  for (int nn = 0; nn < 4; nn++) {
    f32x4 z = {0.f, 0.f, 0.f, 0.f};
    of[nn] = z;
  }
  #pragma unroll
  for (int r = 0; r < 4; r++) { m[r] = -1e30f; l[r] = 0.f; }

  for (int j0 = 0; j0 < SEQ; j0 += 64) {
    __syncthreads();
    #pragma unroll
    for (int it = 0; it < 2; it++) {
      int e8 = it * 256 + tid;
      int key = e8 >> 3, d8 = e8 & 7;
      *reinterpret_cast<bf16x8*>(&Ks[key][d8 * 8]) =
          *reinterpret_cast<const bf16x8*>(&k[base + (size_t)(j0 + key) * EMB + d8 * 8]);
    }
    #pragma unroll
    for (int it = 0; it < 8; it++) {
      int pr = it * 256 + tid;
      int key = pr >> 5, dp = pr & 31;
      unsigned int rv = *reinterpret_cast<const unsigned int*>(
          &v[base + (size_t)(j0 + key) * EMB + dp * 2]);
      Vt[dp * 2][key]     = (unsigned short)(rv & 0xffffu);
      Vt[dp * 2 + 1][key] = (unsigned short)(rv >> 16);
    }
    __syncthreads();

    f32x4 sf[4];
    #pragma unroll
    for (int nn = 0; nn < 4; nn++) {
      bf16x8 kb0 = *reinterpret_cast<const bf16x8*>(&Ks[nn * 16 + lc][lg * 8]);
      bf16x8 kb1 = *reinterpret_cast<const bf16x8*>(&Ks[nn * 16 + lc][32 + lg * 8]);
      f32x4 z = {0.f, 0.f, 0.f, 0.f};
      z = __builtin_amdgcn_mfma_f32_16x16x32_bf16(qa[0], kb0, z, 0, 0, 0);
      z = __builtin_amdgcn_mfma_f32_16x16x32_bf16(qa[1], kb1, z, 0, 0, 0);
      #pragma unroll
      for (int r = 0; r < 4; r++) sf[nn][r] = z[r] * 0.03125f;
    }

    #pragma unroll
    for (int r = 0; r < 4; r++) {
      float t = fmaxf(fmaxf(sf[0][r], sf[1][r]), fmaxf(sf[2][r], sf[3][r]));
      t = fmaxf(t, __shfl_xor(t, 1));
      t = fmaxf(t, __shfl_xor(t, 2));
      t = fmaxf(t, __shfl_xor(t, 4));
      t = fmaxf(t, __shfl_xor(t, 8));
      float mn = fmaxf(m[r], t);
      float sc = __expf(m[r] - mn);
      m[r] = mn;
      float ps = 0.f;
      #pragma unroll
      for (int nn = 0; nn < 4; nn++) {
        float p = __expf(sf[nn][r] - mn);
        sf[nn][r] = p;
        ps += p;
      }
      ps += __shfl_xor(ps, 1);
      ps += __shfl_xor(ps, 2);
      ps += __shfl_xor(ps, 4);
      ps += __shfl_xor(ps, 8);
      l[r] = l[r] * sc + ps;
      #pragma unroll
      for (int nn = 0; nn < 4; nn++) {
        of[nn][r] *= sc;
        Ps[wave][lg * 4 + r][nn * 16 + lc] = f2bf(sf[nn][r]);
      }
    }

    bf16x8 pa0 = *reinterpret_cast<const bf16x8*>(&Ps[wave][lc][lg * 8]);
    bf16x8 pa1 = *reinterpret_cast<const bf16x8*>(&Ps[wave][lc][32 + lg * 8]);
    #pragma unroll
    for (int nn = 0; nn < 4; nn++) {
      bf16x8 vb0 = *reinterpret_cast<const bf16x8*>(&Vt[nn * 16 + lc][lg * 8]);
      bf16x8 vb1 = *reinterpret_cast<const bf16x8*>(&Vt[nn * 16 + lc][32 + lg * 8]);
      of[nn] = __builtin_amdgcn_mfma_f32_16x16x32_bf16(pa0, vb0, of[nn], 0, 0, 0);
      of[nn] = __builtin_amdgcn_mfma_f32_16x16x32_bf16(pa1, vb1, of[nn], 0, 0, 0);
    }
  }

  #pragma unroll
  for (int r = 0; r < 4; r++) {
    float rl = 1.0f / l[r];
    #pragma unroll
    for (int nn = 0; nn < 4; nn++)
      ctx[base + (size_t)(q0 + lg * 4 + r) * EMB + nn * 16 + lc] = f2bf(of[nn][r] * rl);
  }
}

// ---------------------------------------------------------------------------
// K3: bf16 MFMA GEMM (m97 structure): out[t][c] = sum_i X[t][i]*W[c][i] + ...
// 128x128 tile, BK=32, 4 waves (2x2), each wave 64x64 via 4x4 16x16 frags.
// ---------------------------------------------------------------------------
template <int K, bool RELU, bool RES, bool OBF>
__global__ __launch_bounds__(256) void gemm_mfma(
    const unsigned short* __restrict__ X, const unsigned short* __restrict__ W,
    const float* __restrict__ bias, const float* __restrict__ resid,
    void* __restrict__ outp, int Nout) {
  __shared__ unsigned short As[128 * 32];
  __shared__ unsigned short Bs[128 * 32];
  const int tid = threadIdx.x;
  const int w = tid >> 6, lane = tid & 63;
  const int lg = lane >> 4, lc = lane & 15;
  const int wr = w >> 1, wc = w & 1;
  const int c0 = blockIdx.x * 128, t0 = blockIdx.y * 128;
  const int srow = lane >> 2;          // 0..15 within a 16-row slab
  const int scol = (lane & 3) * 8;     // 0,8,16,24

  f32x4 acc[4][4];
  #pragma unroll
  for (int m = 0; m < 4; m++)
    #pragma unroll
    for (int n = 0; n < 4; n++) {
      f32x4 z = {0.f, 0.f, 0.f, 0.f};
      acc[m][n] = z;
    }

  for (int i0 = 0; i0 < K; i0 += 32) {
    __syncthreads();
    #pragma unroll
    for (int c = 0; c < 2; c++) {
      const int slab = w * 2 + c;            // 0..7, 16 rows each
      gload_lds16(&X[(size_t)(t0 + slab * 16 + srow) * K + i0 + scol],
                  &As[slab * 512]);
      gload_lds16(&W[(size_t)(c0 + slab * 16 + srow) * K + i0 + scol],
                  &Bs[slab * 512]);
    }
    __syncthreads();
    bf16x8 a[4], b[4];
    #pragma unroll
    for (int m = 0; m < 4; m++)
      a[m] = *reinterpret_cast<const bf16x8*>(&As[(wr * 64 + m * 16 + lc) * 32 + lg * 8]);
    #pragma unroll
    for (int n = 0; n < 4; n++)
      b[n] = *reinterpret_cast<const bf16x8*>(&Bs[(wc * 64 + n * 16 + lc) * 32 + lg * 8]);
    #pragma unroll
    for (int m = 0; m < 4; m++)
      #pragma unroll
      for (int n = 0; n < 4; n++)
        acc[m][n] = __builtin_amdgcn_mfma_f32_16x16x32_bf16(a[m], b[n], acc[m][n], 0, 0, 0);
  }

  float* outf = (float*)outp;
  unsigned short* outb = (unsigned short*)outp;
  #pragma unroll
  for (int m = 0; m < 4; m++) {
    #pragma unroll
    for (int r = 0; r < 4; r++) {
      int row = t0 + wr * 64 + m * 16 + lg * 4 + r;
      #pragma unroll
      for (int n = 0; n < 4; n++) {
        int col = c0 + wc * 64 + n * 16 + lc;
        float val = acc[m][n][r] + bias[col];
        if constexpr (RES) val += resid[(size_t)row * Nout + col];
        if constexpr (RELU) val = fmaxf(val, 0.f);
        if constexpr (OBF) outb[(size_t)row * Nout + col] = f2bf(val);
        else outf[(size_t)row * Nout + col] = val;
      }
    }
  }
}

// ---------------------------------------------------------------------------
// K4: in-place LayerNorm over rows of width 1024 (+ optional bf16 copy).
// ---------------------------------------------------------------------------
__global__ __launch_bounds__(256) void ln_kernel(
    float* __restrict__ io, const float* __restrict__ g,
    const float* __restrict__ b, unsigned short* __restrict__ ob) {
  __shared__ float sw[4], ssw[4];
  const int tid = threadIdx.x;
  const int row = blockIdx.x;
  const int wave = tid >> 6, lane = tid & 63;
  float vals[4];
  float s = 0.f, ss = 0.f;
  #pragma unroll
  for (int j = 0; j < 4; j++) {
    float vv = io[(size_t)row * EMB + tid + 256 * j];
    vals[j] = vv; s += vv; ss += vv * vv;
  }
  #pragma unroll
  for (int off = 32; off >= 1; off >>= 1) {
    s += __shfl_xor(s, off, 64);
    ss += __shfl_xor(ss, off, 64);
  }
  if (lane == 0) { sw[wave] = s; ssw[wave] = ss; }
  __syncthreads();
  float st = sw[0] + sw[1] + sw[2] + sw[3];
  float sst = ssw[0] + ssw[1] + ssw[2] + ssw[3];
  float mu = st * (1.f / EMB);
  float var = sst * (1.f / EMB) - mu * mu;
  float rs = rsqrtf(var + 1e-5f);
  #pragma unroll
  for (int j = 0; j < 4; j++) {
    int e = tid + 256 * j;
    float r = (vals[j] - mu) * rs * g[e] + b[e];
    io[(size_t)row * EMB + e] = r;
    if (ob) ob[(size_t)row * EMB + e] = f2bf(r);
  }
}

// ---------------------------------------------------------------------------
extern "C" void kernel_launch(void* const* d_in, const int* in_sizes, int n_in,
                              void* d_out, int out_size, void* d_ws, size_t ws_size,
                              hipStream_t stream) {
  const float* x    = (const float*)d_in[0];
  const float* Wq   = (const float*)d_in[1];
  const float* Wk   = (const float*)d_in[2];
  const float* Wv   = (const float*)d_in[3];
  const float* Wo   = (const float*)d_in[4];
  const float* bo   = (const float*)d_in[5];
  const float* ln1g = (const float*)d_in[6];
  const float* ln1b = (const float*)d_in[7];
  const float* ln2g = (const float*)d_in[8];
  const float* ln2b = (const float*)d_in[9];
  const float* W1   = (const float*)d_in[10];
  const float* b1   = (const float*)d_in[11];
  const float* W2   = (const float*)d_in[12];
  const float* b2   = (const float*)d_in[13];
  float* out = (float*)d_out;

  const size_t TE = (size_t)TOKENS * EMB;          // 4M elems
  const size_t MB = 1024 * 1024;
  // [0,8)MB qb | [8,16) kb | [16,24) vb | [24,32) ctx   (all bf16)
  unsigned short* qb  = (unsigned short*)d_ws;
  unsigned short* kb  = qb + TE;
  unsigned short* vb  = kb + TE;
  unsigned short* ctx = vb + TE;
  // ff1 bf16 [0,32)MB — reuses qb..ctx after GEMM1
  unsigned short* ff1 = (unsigned short*)d_ws;
  // x1 f32 [32,48)MB ; x1b bf16 [48,56)MB
  float*          x1  = (float*)((char*)d_ws + 32 * MB);
  unsigned short* x1b = (unsigned short*)((char*)d_ws + 48 * MB);
  // bf16 weights: Wo [56,58) | W1 [58,66) | W2 [66,74)
  unsigned short* Wob = (unsigned short*)((char*)d_ws + 56 * MB);
  unsigned short* W1b = (unsigned short*)((char*)d_ws + 58 * MB);
  unsigned short* W2b = (unsigned short*)((char*)d_ws + 66 * MB);

  cvt_kernel<<<EMB * EMB / 2048, 256, 0, stream>>>(Wo, Wob, EMB * EMB);
  cvt_kernel<<<FFN_D * EMB / 2048, 256, 0, stream>>>(W1, W1b, FFN_D * EMB);
  cvt_kernel<<<FFN_D * EMB / 2048, 256, 0, stream>>>(W2, W2b, FFN_D * EMB);

  qkv_kernel<<<1024, 256, 0, stream>>>(x, Wq, Wk, Wv, qb, kb, vb);
  attn_mfma<<<1024, 256, 0, stream>>>(qb, kb, vb, ctx);
  // x1 = ctx @ Wo.T + bo + x (f32 out), then LN in place (+bf16 copy)
  gemm_mfma<1024, false, true, false>
      <<<dim3(EMB / 128, TOKENS / 128), 256, 0, stream>>>(ctx, Wob, bo, x, x1, EMB);
  ln_kernel<<<TOKENS, 256, 0, stream>>>(x1, ln1g, ln1b, x1b);
  // ff1 = relu(x1 @ W1.T + b1) (bf16 out)
  gemm_mfma<1024, true, false, true>
      <<<dim3(FFN_D / 128, TOKENS / 128), 256, 0, stream>>>(x1b, W1b, b1, nullptr, ff1, FFN_D);
  // out = ff1 @ W2.T + b2 + x1 (f32 out), then LN in place
  gemm_mfma<4096, false, true, false>
      <<<dim3(EMB / 128, TOKENS / 128), 256, 0, stream>>>(ff1, W2b, b2, x1, out, EMB);
  ln_kernel<<<TOKENS, 256, 0, stream>>>(out, ln2g, ln2b, nullptr);
}

// Round 4
// 382.543 us; speedup vs baseline: 8.2442x; 1.1454x over previous
//
#include <hip/hip_runtime.h>
#include <hip/hip_bf16.h>

#define TOKENS 4096   // N*S = 2*2048
#define EMB    1024
#define SEQ    2048
#define NHEAD  16
#define HDIM   64
#define FFN_D  4096

typedef __attribute__((ext_vector_type(8))) short bf16x8;
typedef __attribute__((ext_vector_type(4))) float f32x4;

static __device__ __forceinline__ unsigned short f2bf(float f) {
  unsigned int u = __float_as_uint(f);
  unsigned int r = (u + 0x7fffu + ((u >> 16) & 1u)) >> 16;  // RNE
  return (unsigned short)r;
}

// async global->LDS, 16B per lane; LDS dest = wave-uniform base + lane*16
static __device__ __forceinline__ void gload_lds16(const unsigned short* g,
                                                   unsigned short* l) {
  __builtin_amdgcn_global_load_lds(
      (const __attribute__((address_space(1))) void*)g,
      (__attribute__((address_space(3))) void*)l, 16, 0, 0);
}

// ---------------------------------------------------------------------------
// K0: f32 -> bf16 convert (weights), 8 elems/thread
// ---------------------------------------------------------------------------
__global__ __launch_bounds__(256) void cvt_kernel(
    const float* __restrict__ in, unsigned short* __restrict__ out, int n) {
  int i = (blockIdx.x * 256 + threadIdx.x) * 8;
  if (i >= n) return;
  float4 v0 = *reinterpret_cast<const float4*>(&in[i]);
  float4 v1 = *reinterpret_cast<const float4*>(&in[i + 4]);
  bf16x8 ov;
  ov[0] = (short)f2bf(v0.x); ov[1] = (short)f2bf(v0.y);
  ov[2] = (short)f2bf(v0.z); ov[3] = (short)f2bf(v0.w);
  ov[4] = (short)f2bf(v1.x); ov[5] = (short)f2bf(v1.y);
  ov[6] = (short)f2bf(v1.z); ov[7] = (short)f2bf(v1.w);
  *reinterpret_cast<bf16x8*>(&out[i]) = ov;
}

// ---------------------------------------------------------------------------
// K1: per-head-dim shared QKV projection -> bf16 outputs.
// ---------------------------------------------------------------------------
__global__ __launch_bounds__(256) void qkv_kernel(
    const float* __restrict__ x,
    const float* __restrict__ Wq, const float* __restrict__ Wk,
    const float* __restrict__ Wv,
    unsigned short* __restrict__ q, unsigned short* __restrict__ k,
    unsigned short* __restrict__ v) {
  __shared__ float WqT[64][65], WkT[64][65], WvT[64][65];
  __shared__ float xs[1024];
  const int tid = threadIdx.x;
  #pragma unroll
  for (int r = 0; r < 16; r++) {
    int idx = tid + 256 * r;        // idx = e*64 + d
    int e = idx >> 6, d = idx & 63;
    WqT[d][e] = Wq[idx];
    WkT[d][e] = Wk[idx];
    WvT[d][e] = Wv[idx];
  }
  for (int tkn = blockIdx.x; tkn < TOKENS; tkn += gridDim.x) {
    __syncthreads();
    #pragma unroll
    for (int j = 0; j < 4; j++)
      xs[tid + 256 * j] = x[(size_t)tkn * EMB + tid + 256 * j];
    __syncthreads();
    #pragma unroll
    for (int j = 0; j < 4; j++) {
      int ef = tid + 256 * j;
      int h = ef >> 6, ed = ef & 63;
      float aq = 0.f, ak = 0.f, av = 0.f;
      #pragma unroll
      for (int d = 0; d < 64; d++) {
        float xv = xs[h * 64 + d];
        aq += xv * WqT[d][ed];
        ak += xv * WkT[d][ed];
        av += xv * WvT[d][ed];
      }
      size_t o = (size_t)tkn * EMB + ef;
      q[o] = f2bf(aq); k[o] = f2bf(ak); v[o] = f2bf(av);
    }
  }
}

// ---------------------------------------------------------------------------
// K1b: transpose V per (n,h): vT[n][h][d][s] from v[n][s][h*64+d]
// ---------------------------------------------------------------------------
__global__ __launch_bounds__(256) void vtrans_kernel(
    const unsigned short* __restrict__ v, unsigned short* __restrict__ vT) {
  __shared__ unsigned short Ts[64][72];
  const int tid = threadIdx.x;
  const int b = blockIdx.x;           // 2*16*32
  const int st = b & 31, nh = b >> 5;
  const int n = nh >> 4, h = nh & 15;
  const int s0 = st * 64;
  const size_t ibase = ((size_t)n * SEQ + s0) * EMB + h * 64;
  #pragma unroll
  for (int it = 0; it < 2; it++) {
    int idx = it * 256 + tid;
    int s = idx >> 3, d8 = idx & 7;
    *reinterpret_cast<bf16x8*>(&Ts[s][d8 * 8]) =
        *reinterpret_cast<const bf16x8*>(&v[ibase + (size_t)s * EMB + d8 * 8]);
  }
  __syncthreads();
  const size_t obase = ((size_t)(n * 16 + h) * 64) * SEQ + s0;
  #pragma unroll
  for (int it = 0; it < 2; it++) {
    int idx = it * 256 + tid;
    int d = idx >> 3, s8 = idx & 7;
    bf16x8 ov;
    #pragma unroll
    for (int i = 0; i < 8; i++) ov[i] = (short)Ts[s8 * 8 + i][d];
    *reinterpret_cast<bf16x8*>(&vT[obase + (size_t)d * SEQ + s8 * 8]) = ov;
  }
}

// ---------------------------------------------------------------------------
// K2: MFMA flash attention, double-buffered swizzled LDS staging.
// KV tile 64; K LDS [64 key][8 slot] with slot^= key&7; Vt LDS [64 dim][8 slot]
// (slot = key8) with slot ^= dim&7; Ps per-wave [16 q][8 slot] slot ^= q&7.
// global_load_lds writes linear; swizzle realized by permuting GLOBAL source.
// ---------------------------------------------------------------------------
__global__ __launch_bounds__(256) void attn_mfma(
    const unsigned short* __restrict__ qg, const unsigned short* __restrict__ kg,
    const unsigned short* __restrict__ vtg, unsigned short* __restrict__ ctx) {
  __shared__ unsigned short Ks[2][4096];
  __shared__ unsigned short Vt[2][4096];
  __shared__ unsigned short Ps[4][1024];
  const int tid = threadIdx.x;
  const int w = tid >> 6, lane = tid & 63;
  const int lg = lane >> 4, lc = lane & 15;
  const int l3 = lane >> 3, l7 = lane & 7;
  const int swz = lc & 7;
  const int b = blockIdx.x;
  const int qt = b & 31, nh = b >> 5;
  const int n = nh >> 4, h = nh & 15;
  const size_t base = (size_t)n * SEQ * EMB + h * 64;
  const size_t vtbase = (size_t)(n * 16 + h) * 64 * SEQ;
  const int q0 = qt * 64 + w * 16;
  const int dimsw = (l7 ^ l3) * 8;    // pre-swizzled offset for staging

  bf16x8 qa0 = *reinterpret_cast<const bf16x8*>(&qg[base + (size_t)(q0 + lc) * EMB + lg * 8]);
  bf16x8 qa1 = *reinterpret_cast<const bf16x8*>(&qg[base + (size_t)(q0 + lc) * EMB + 32 + lg * 8]);

  f32x4 of[4];
  float m[4], l[4];
  #pragma unroll
  for (int nn = 0; nn < 4; nn++) {
    f32x4 z = {0.f, 0.f, 0.f, 0.f};
    of[nn] = z;
  }
  #pragma unroll
  for (int r = 0; r < 4; r++) { m[r] = -1e30f; l[r] = 0.f; }

  // stage one 64-key tile into buffer bi: 4 gload_lds16 per wave
  auto stage = [&](int bi, int t) {
    const int j0 = t * 64;
    unsigned short* kd = &Ks[bi][0];
    unsigned short* vd = &Vt[bi][0];
    #pragma unroll
    for (int c2 = 0; c2 < 2; c2++) {
      const int c = 2 * w + c2;
      gload_lds16(&kg[base + (size_t)(j0 + c * 8 + l3) * EMB + dimsw], kd + c * 512);
      gload_lds16(&vtg[vtbase + (size_t)(c * 8 + l3) * SEQ + j0 + dimsw], vd + c * 512);
    }
  };

  stage(0, 0);
  #pragma unroll 1
  for (int t = 0; t < SEQ / 64; ++t) {
    if (t < SEQ / 64 - 1) {
      stage((t + 1) & 1, t + 1);
      asm volatile("s_waitcnt vmcnt(4)" ::: "memory");
    } else {
      asm volatile("s_waitcnt vmcnt(0)" ::: "memory");
    }
    __builtin_amdgcn_sched_barrier(0);
    __builtin_amdgcn_s_barrier();
    __builtin_amdgcn_sched_barrier(0);

    const unsigned short* KsB = &Ks[t & 1][0];
    const unsigned short* VtB = &Vt[t & 1][0];
    unsigned short* PsW = &Ps[w][0];

    // S = Q K^T / 32
    f32x4 sf[4];
    #pragma unroll
    for (int nn = 0; nn < 4; nn++) {
      const int row = nn * 16 + lc;
      bf16x8 kb0 = *reinterpret_cast<const bf16x8*>(&KsB[row * 64 + (lg ^ swz) * 8]);
      bf16x8 kb1 = *reinterpret_cast<const bf16x8*>(&KsB[row * 64 + (((4 | lg)) ^ swz) * 8]);
      f32x4 z = {0.f, 0.f, 0.f, 0.f};
      z = __builtin_amdgcn_mfma_f32_16x16x32_bf16(qa0, kb0, z, 0, 0, 0);
      z = __builtin_amdgcn_mfma_f32_16x16x32_bf16(qa1, kb1, z, 0, 0, 0);
      #pragma unroll
      for (int r = 0; r < 4; r++) sf[nn][r] = z[r] * 0.03125f;
    }

    // online softmax; P written to wave-private swizzled LDS
    #pragma unroll
    for (int rr = 0; rr < 4; rr++) {
      float tm = fmaxf(fmaxf(sf[0][rr], sf[1][rr]), fmaxf(sf[2][rr], sf[3][rr]));
      tm = fmaxf(tm, __shfl_xor(tm, 1));
      tm = fmaxf(tm, __shfl_xor(tm, 2));
      tm = fmaxf(tm, __shfl_xor(tm, 4));
      tm = fmaxf(tm, __shfl_xor(tm, 8));
      float mn = fmaxf(m[rr], tm);
      float sc = __expf(m[rr] - mn);
      m[rr] = mn;
      float ps = 0.f;
      #pragma unroll
      for (int nn = 0; nn < 4; nn++) {
        float p = __expf(sf[nn][rr] - mn);
        sf[nn][rr] = p;
        ps += p;
      }
      ps += __shfl_xor(ps, 1);
      ps += __shfl_xor(ps, 2);
      ps += __shfl_xor(ps, 4);
      ps += __shfl_xor(ps, 8);
      l[rr] = l[rr] * sc + ps;
      const int qq = lg * 4 + rr;
      #pragma unroll
      for (int nn = 0; nn < 4; nn++) {
        of[nn][rr] *= sc;
        const int sl = (nn * 2 + (lc >> 3)) ^ (qq & 7);
        PsW[qq * 64 + sl * 8 + (lc & 7)] = f2bf(sf[nn][rr]);
      }
    }

    // O += P V
    bf16x8 pa0 = *reinterpret_cast<const bf16x8*>(&PsW[lc * 64 + (lg ^ swz) * 8]);
    bf16x8 pa1 = *reinterpret_cast<const bf16x8*>(&PsW[lc * 64 + ((4 | lg) ^ swz) * 8]);
    #pragma unroll
    for (int nn = 0; nn < 4; nn++) {
      const int row = nn * 16 + lc;
      bf16x8 vb0 = *reinterpret_cast<const bf16x8*>(&VtB[row * 64 + (lg ^ swz) * 8]);
      bf16x8 vb1 = *reinterpret_cast<const bf16x8*>(&VtB[row * 64 + ((4 | lg) ^ swz) * 8]);
      of[nn] = __builtin_amdgcn_mfma_f32_16x16x32_bf16(pa0, vb0, of[nn], 0, 0, 0);
      of[nn] = __builtin_amdgcn_mfma_f32_16x16x32_bf16(pa1, vb1, of[nn], 0, 0, 0);
    }

    if (t < SEQ / 64 - 1) {
      __builtin_amdgcn_sched_barrier(0);
      __builtin_amdgcn_s_barrier();   // all waves done reading before next stage
    }
  }

  #pragma unroll
  for (int r = 0; r < 4; r++) {
    float rl = 1.0f / l[r];
    #pragma unroll
    for (int nn = 0; nn < 4; nn++)
      ctx[base + (size_t)(q0 + lg * 4 + r) * EMB + nn * 16 + lc] = f2bf(of[nn][r] * rl);
  }
}

// ---------------------------------------------------------------------------
// K3: bf16 MFMA GEMM (m97 structure): out[t][c] = sum_i X[t][i]*W[c][i] + ...
// ---------------------------------------------------------------------------
template <int K, bool RELU, bool RES, bool OBF>
__global__ __launch_bounds__(256) void gemm_mfma(
    const unsigned short* __restrict__ X, const unsigned short* __restrict__ W,
    const float* __restrict__ bias, const float* __restrict__ resid,
    void* __restrict__ outp, int Nout) {
  __shared__ unsigned short As[128 * 32];
  __shared__ unsigned short Bs[128 * 32];
  const int tid = threadIdx.x;
  const int w = tid >> 6, lane = tid & 63;
  const int lg = lane >> 4, lc = lane & 15;
  const int wr = w >> 1, wc = w & 1;
  const int c0 = blockIdx.x * 128, t0 = blockIdx.y * 128;
  const int srow = lane >> 2;
  const int scol = (lane & 3) * 8;

  f32x4 acc[4][4];
  #pragma unroll
  for (int m = 0; m < 4; m++)
    #pragma unroll
    for (int n = 0; n < 4; n++) {
      f32x4 z = {0.f, 0.f, 0.f, 0.f};
      acc[m][n] = z;
    }

  for (int i0 = 0; i0 < K; i0 += 32) {
    __syncthreads();
    #pragma unroll
    for (int c = 0; c < 2; c++) {
      const int slab = w * 2 + c;
      gload_lds16(&X[(size_t)(t0 + slab * 16 + srow) * K + i0 + scol],
                  &As[slab * 512]);
      gload_lds16(&W[(size_t)(c0 + slab * 16 + srow) * K + i0 + scol],
                  &Bs[slab * 512]);
    }
    __syncthreads();
    bf16x8 a[4], b[4];
    #pragma unroll
    for (int m = 0; m < 4; m++)
      a[m] = *reinterpret_cast<const bf16x8*>(&As[(wr * 64 + m * 16 + lc) * 32 + lg * 8]);
    #pragma unroll
    for (int n = 0; n < 4; n++)
      b[n] = *reinterpret_cast<const bf16x8*>(&Bs[(wc * 64 + n * 16 + lc) * 32 + lg * 8]);
    #pragma unroll
    for (int m = 0; m < 4; m++)
      #pragma unroll
      for (int n = 0; n < 4; n++)
        acc[m][n] = __builtin_amdgcn_mfma_f32_16x16x32_bf16(a[m], b[n], acc[m][n], 0, 0, 0);
  }

  float* outf = (float*)outp;
  unsigned short* outb = (unsigned short*)outp;
  #pragma unroll
  for (int m = 0; m < 4; m++) {
    #pragma unroll
    for (int r = 0; r < 4; r++) {
      int row = t0 + wr * 64 + m * 16 + lg * 4 + r;
      #pragma unroll
      for (int n = 0; n < 4; n++) {
        int col = c0 + wc * 64 + n * 16 + lc;
        float val = acc[m][n][r] + bias[col];
        if constexpr (RES) val += resid[(size_t)row * Nout + col];
        if constexpr (RELU) val = fmaxf(val, 0.f);
        if constexpr (OBF) outb[(size_t)row * Nout + col] = f2bf(val);
        else outf[(size_t)row * Nout + col] = val;
      }
    }
  }
}

// ---------------------------------------------------------------------------
// K4: in-place LayerNorm over rows of width 1024 (+ optional bf16 copy).
// ---------------------------------------------------------------------------
__global__ __launch_bounds__(256) void ln_kernel(
    float* __restrict__ io, const float* __restrict__ g,
    const float* __restrict__ b, unsigned short* __restrict__ ob) {
  __shared__ float sw[4], ssw[4];
  const int tid = threadIdx.x;
  const int row = blockIdx.x;
  const int wave = tid >> 6, lane = tid & 63;
  float vals[4];
  float s = 0.f, ss = 0.f;
  #pragma unroll
  for (int j = 0; j < 4; j++) {
    float vv = io[(size_t)row * EMB + tid + 256 * j];
    vals[j] = vv; s += vv; ss += vv * vv;
  }
  #pragma unroll
  for (int off = 32; off >= 1; off >>= 1) {
    s += __shfl_xor(s, off, 64);
    ss += __shfl_xor(ss, off, 64);
  }
  if (lane == 0) { sw[wave] = s; ssw[wave] = ss; }
  __syncthreads();
  float st = sw[0] + sw[1] + sw[2] + sw[3];
  float sst = ssw[0] + ssw[1] + ssw[2] + ssw[3];
  float mu = st * (1.f / EMB);
  float var = sst * (1.f / EMB) - mu * mu;
  float rs = rsqrtf(var + 1e-5f);
  #pragma unroll
  for (int j = 0; j < 4; j++) {
    int e = tid + 256 * j;
    float r = (vals[j] - mu) * rs * g[e] + b[e];
    io[(size_t)row * EMB + e] = r;
    if (ob) ob[(size_t)row * EMB + e] = f2bf(r);
  }
}

// ---------------------------------------------------------------------------
extern "C" void kernel_launch(void* const* d_in, const int* in_sizes, int n_in,
                              void* d_out, int out_size, void* d_ws, size_t ws_size,
                              hipStream_t stream) {
  const float* x    = (const float*)d_in[0];
  const float* Wq   = (const float*)d_in[1];
  const float* Wk   = (const float*)d_in[2];
  const float* Wv   = (const float*)d_in[3];
  const float* Wo   = (const float*)d_in[4];
  const float* bo   = (const float*)d_in[5];
  const float* ln1g = (const float*)d_in[6];
  const float* ln1b = (const float*)d_in[7];
  const float* ln2g = (const float*)d_in[8];
  const float* ln2b = (const float*)d_in[9];
  const float* W1   = (const float*)d_in[10];
  const float* b1   = (const float*)d_in[11];
  const float* W2   = (const float*)d_in[12];
  const float* b2   = (const float*)d_in[13];
  float* out = (float*)d_out;

  const size_t TE = (size_t)TOKENS * EMB;
  const size_t MB = 1024 * 1024;
  // [0,8)MB qb | [8,16) kb | [16,24) vb | [24,32) ctx  (bf16)
  unsigned short* qb  = (unsigned short*)d_ws;
  unsigned short* kb  = qb + TE;
  unsigned short* vb  = kb + TE;
  unsigned short* ctx = vb + TE;
  // ff1 bf16 [0,32)MB — reuses qb..ctx after attention
  unsigned short* ff1 = (unsigned short*)d_ws;
  // x1 f32 [32,48)MB (written post-attn); vT bf16 aliases [32,40) pre-attn
  float*          x1  = (float*)((char*)d_ws + 32 * MB);
  unsigned short* vT  = (unsigned short*)((char*)d_ws + 32 * MB);
  unsigned short* x1b = (unsigned short*)((char*)d_ws + 48 * MB);
  unsigned short* Wob = (unsigned short*)((char*)d_ws + 56 * MB);
  unsigned short* W1b = (unsigned short*)((char*)d_ws + 58 * MB);
  unsigned short* W2b = (unsigned short*)((char*)d_ws + 66 * MB);

  cvt_kernel<<<EMB * EMB / 2048, 256, 0, stream>>>(Wo, Wob, EMB * EMB);
  cvt_kernel<<<FFN_D * EMB / 2048, 256, 0, stream>>>(W1, W1b, FFN_D * EMB);
  cvt_kernel<<<FFN_D * EMB / 2048, 256, 0, stream>>>(W2, W2b, FFN_D * EMB);

  qkv_kernel<<<1024, 256, 0, stream>>>(x, Wq, Wk, Wv, qb, kb, vb);
  vtrans_kernel<<<1024, 256, 0, stream>>>(vb, vT);
  attn_mfma<<<1024, 256, 0, stream>>>(qb, kb, vT, ctx);
  gemm_mfma<1024, false, true, false>
      <<<dim3(EMB / 128, TOKENS / 128), 256, 0, stream>>>(ctx, Wob, bo, x, x1, EMB);
  ln_kernel<<<TOKENS, 256, 0, stream>>>(x1, ln1g, ln1b, x1b);
  gemm_mfma<1024, true, false, true>
      <<<dim3(FFN_D / 128, TOKENS / 128), 256, 0, stream>>>(x1b, W1b, b1, nullptr, ff1, FFN_D);
  gemm_mfma<4096, false, true, false>
      <<<dim3(EMB / 128, TOKENS / 128), 256, 0, stream>>>(ff1, W2b, b2, x1, out, EMB);
  ln_kernel<<<TOKENS, 256, 0, stream>>>(out, ln2g, ln2b, nullptr);
}

// Round 5
// 353.056 us; speedup vs baseline: 8.9328x; 1.0835x over previous
//
#include <hip/hip_runtime.h>
#include <hip/hip_bf16.h>

#define TOKENS 4096   // N*S = 2*2048
#define EMB    1024
#define SEQ    2048
#define NHEAD  16
#define HDIM   64
#define FFN_D  4096

typedef __attribute__((ext_vector_type(8))) short bf16x8;
typedef __attribute__((ext_vector_type(4))) float f32x4;
typedef __attribute__((ext_vector_type(16))) float f32x16;

static __device__ __forceinline__ unsigned short f2bf(float f) {
  unsigned int u = __float_as_uint(f);
  unsigned int r = (u + 0x7fffu + ((u >> 16) & 1u)) >> 16;  // RNE
  return (unsigned short)r;
}

static __device__ __forceinline__ unsigned int pk2(float a, float b) {
  __hip_bfloat162 h = __float22bfloat162_rn(float2{a, b});
  return *reinterpret_cast<unsigned int*>(&h);
}

// async global->LDS, 16B per lane; LDS dest = wave-uniform base + lane*16
static __device__ __forceinline__ void gload_lds16(const unsigned short* g,
                                                   unsigned short* l) {
  __builtin_amdgcn_global_load_lds(
      (const __attribute__((address_space(1))) void*)g,
      (__attribute__((address_space(3))) void*)l, 16, 0, 0);
}

// ---------------------------------------------------------------------------
// K0: f32 -> bf16 convert (weights), 8 elems/thread
// ---------------------------------------------------------------------------
__global__ __launch_bounds__(256) void cvt_kernel(
    const float* __restrict__ in, unsigned short* __restrict__ out, int n) {
  int i = (blockIdx.x * 256 + threadIdx.x) * 8;
  if (i >= n) return;
  float4 v0 = *reinterpret_cast<const float4*>(&in[i]);
  float4 v1 = *reinterpret_cast<const float4*>(&in[i + 4]);
  bf16x8 ov;
  ov[0] = (short)f2bf(v0.x); ov[1] = (short)f2bf(v0.y);
  ov[2] = (short)f2bf(v0.z); ov[3] = (short)f2bf(v0.w);
  ov[4] = (short)f2bf(v1.x); ov[5] = (short)f2bf(v1.y);
  ov[6] = (short)f2bf(v1.z); ov[7] = (short)f2bf(v1.w);
  *reinterpret_cast<bf16x8*>(&out[i]) = ov;
}

// ---------------------------------------------------------------------------
// K1: per-head-dim shared QKV projection -> bf16 outputs.
// ---------------------------------------------------------------------------
__global__ __launch_bounds__(256) void qkv_kernel(
    const float* __restrict__ x,
    const float* __restrict__ Wq, const float* __restrict__ Wk,
    const float* __restrict__ Wv,
    unsigned short* __restrict__ q, unsigned short* __restrict__ k,
    unsigned short* __restrict__ v) {
  __shared__ float WqT[64][65], WkT[64][65], WvT[64][65];
  __shared__ float xs[1024];
  const int tid = threadIdx.x;
  #pragma unroll
  for (int r = 0; r < 16; r++) {
    int idx = tid + 256 * r;        // idx = e*64 + d
    int e = idx >> 6, d = idx & 63;
    WqT[d][e] = Wq[idx];
    WkT[d][e] = Wk[idx];
    WvT[d][e] = Wv[idx];
  }
  for (int tkn = blockIdx.x; tkn < TOKENS; tkn += gridDim.x) {
    __syncthreads();
    #pragma unroll
    for (int j = 0; j < 4; j++)
      xs[tid + 256 * j] = x[(size_t)tkn * EMB + tid + 256 * j];
    __syncthreads();
    #pragma unroll
    for (int j = 0; j < 4; j++) {
      int ef = tid + 256 * j;
      int h = ef >> 6, ed = ef & 63;
      float aq = 0.f, ak = 0.f, av = 0.f;
      #pragma unroll
      for (int d = 0; d < 64; d++) {
        float xv = xs[h * 64 + d];
        aq += xv * WqT[d][ed];
        ak += xv * WkT[d][ed];
        av += xv * WvT[d][ed];
      }
      size_t o = (size_t)tkn * EMB + ef;
      q[o] = f2bf(aq); k[o] = f2bf(ak); v[o] = f2bf(av);
    }
  }
}

// ---------------------------------------------------------------------------
// K1b: transpose V per (n,h): vT[n][h][d][s] from v[n][s][h*64+d]
// ---------------------------------------------------------------------------
__global__ __launch_bounds__(256) void vtrans_kernel(
    const unsigned short* __restrict__ v, unsigned short* __restrict__ vT) {
  __shared__ unsigned short Ts[64][72];
  const int tid = threadIdx.x;
  const int b = blockIdx.x;           // 2*16*32
  const int st = b & 31, nh = b >> 5;
  const int n = nh >> 4, h = nh & 15;
  const int s0 = st * 64;
  const size_t ibase = ((size_t)n * SEQ + s0) * EMB + h * 64;
  #pragma unroll
  for (int it = 0; it < 2; it++) {
    int idx = it * 256 + tid;
    int s = idx >> 3, d8 = idx & 7;
    *reinterpret_cast<bf16x8*>(&Ts[s][d8 * 8]) =
        *reinterpret_cast<const bf16x8*>(&v[ibase + (size_t)s * EMB + d8 * 8]);
  }
  __syncthreads();
  const size_t obase = ((size_t)(n * 16 + h) * 64) * SEQ + s0;
  #pragma unroll
  for (int it = 0; it < 2; it++) {
    int idx = it * 256 + tid;
    int d = idx >> 3, s8 = idx & 7;
    bf16x8 ov;
    #pragma unroll
    for (int i = 0; i < 8; i++) ov[i] = (short)Ts[s8 * 8 + i][d];
    *reinterpret_cast<bf16x8*>(&vT[obase + (size_t)d * SEQ + s8 * 8]) = ov;
  }
}

// ---------------------------------------------------------------------------
// K2: MFMA flash attention, swapped-operand 32x32x16 design.
// S^T = mfma(K, Q): lane owns q = lane&31; row-softmax is in-lane + 1 shuffle.
// O^T = mfma(V^T, P^T): cols = q = lane&31 -> rescale/epilogue lane-local.
// LDS tiles granule(8 ushort)-XOR swizzled: stored_g = g ^ (row&7); staging
// realizes it by pre-swizzling the GLOBAL source (linear LDS dest, rule #21).
// ---------------------------------------------------------------------------
__global__ __launch_bounds__(256) void attn_mfma(
    const unsigned short* __restrict__ qg, const unsigned short* __restrict__ kg,
    const unsigned short* __restrict__ vtg, unsigned short* __restrict__ ctx) {
  __shared__ unsigned short Ks[2][4096];   // [64 key][8 granules of 8 dims]
  __shared__ unsigned short Vt[2][4096];   // [64 dim][8 granules of 8 keys]
  __shared__ unsigned short Ps[4][2048];   // per wave: [32 q][8 granules of 8 keys]
  const int tid = threadIdx.x;
  const int w = tid >> 6, lane = tid & 63;
  const int l31 = lane & 31, h5 = lane >> 5;
  const int q7 = l31 & 7;
  const int b = blockIdx.x;
  const int qt = b & 15, nh = b >> 4;
  const int n = nh >> 4, h = nh & 15;
  const size_t base = (size_t)n * SEQ * EMB + h * 64;
  const size_t vtbase = (size_t)(n * 16 + h) * 64 * SEQ;
  const int q0 = qt * 128 + w * 32;

  // Q B-fragments: lane holds Q[q0+l31][d = 16t + 8*h5 + j]
  bf16x8 qa[4];
  #pragma unroll
  for (int t = 0; t < 4; t++)
    qa[t] = *reinterpret_cast<const bf16x8*>(
        &qg[base + (size_t)(q0 + l31) * EMB + 16 * t + 8 * h5]);

  f32x16 o0 = {}, o1 = {};
  float m = -1e30f, l = 0.f;

  auto stage = [&](int bi, int t) {
    const int j0 = t * 64;
    #pragma unroll
    for (int rnd = 0; rnd < 2; rnd++) {
      const int glbase = rnd * 256 + w * 64;      // wave-uniform granule base
      const int gl = glbase + lane;
      const int row = gl >> 3, gp = gl & 7;
      const int gsrc = (gp ^ (row & 7)) * 8;      // pre-swizzled global offset
      gload_lds16(&kg[base + (size_t)(j0 + row) * EMB + gsrc], &Ks[bi][glbase * 8]);
      gload_lds16(&vtg[vtbase + (size_t)row * SEQ + j0 + gsrc], &Vt[bi][glbase * 8]);
    }
  };

  stage(0, 0);
  #pragma unroll 1
  for (int t = 0; t < SEQ / 64; ++t) {
    if (t < SEQ / 64 - 1) {
      stage((t + 1) & 1, t + 1);
      asm volatile("s_waitcnt vmcnt(4)" ::: "memory");
    } else {
      asm volatile("s_waitcnt vmcnt(0)" ::: "memory");
    }
    __builtin_amdgcn_sched_barrier(0);
    __builtin_amdgcn_s_barrier();
    __builtin_amdgcn_sched_barrier(0);

    const unsigned short* KsB = &Ks[t & 1][0];
    const unsigned short* VtB = &Vt[t & 1][0];
    unsigned short* PsW = &Ps[w][0];

    // ---- S^T = K Q^T (scaled later): rows=64 keys (2 subtiles), cols=32 q
    f32x16 s0 = {}, s1 = {};
    __builtin_amdgcn_s_setprio(1);
    #pragma unroll
    for (int tt = 0; tt < 4; tt++) {
      const int g = (2 * tt + h5);
      bf16x8 ka0 = *reinterpret_cast<const bf16x8*>(
          &KsB[l31 * 64 + (g ^ q7) * 8]);
      bf16x8 ka1 = *reinterpret_cast<const bf16x8*>(
          &KsB[(32 + l31) * 64 + (g ^ q7) * 8]);
      s0 = __builtin_amdgcn_mfma_f32_32x32x16_bf16(ka0, qa[tt], s0, 0, 0, 0);
      s1 = __builtin_amdgcn_mfma_f32_32x32x16_bf16(ka1, qa[tt], s1, 0, 0, 0);
    }
    __builtin_amdgcn_s_setprio(0);

    // ---- online softmax for q = q0 + l31 (in-lane over 32 scores + 1 shfl)
    #pragma unroll
    for (int r = 0; r < 16; r++) { s0[r] *= 0.03125f; s1[r] *= 0.03125f; }
    float tm = -1e30f;
    #pragma unroll
    for (int r = 0; r < 16; r++) tm = fmaxf(tm, fmaxf(s0[r], s1[r]));
    tm = fmaxf(tm, __shfl_xor(tm, 32));
    const float mn = fmaxf(m, tm);
    const float sc = __expf(m - mn);
    m = mn;
    float ps = 0.f;
    #pragma unroll
    for (int r = 0; r < 16; r++) {
      s0[r] = __expf(s0[r] - mn); ps += s0[r];
      s1[r] = __expf(s1[r] - mn); ps += s1[r];
    }
    ps += __shfl_xor(ps, 32);
    l = l * sc + ps;
    #pragma unroll
    for (int r = 0; r < 16; r++) { o0[r] *= sc; o1[r] *= sc; }

    // ---- pack P^T -> LDS [q=l31][key], b64 writes, granule-XOR swizzle
    #pragma unroll
    for (int s = 0; s < 2; s++) {
      #pragma unroll
      for (int rg = 0; rg < 4; rg++) {
        float p0 = s ? s1[4 * rg] : s0[4 * rg];
        float p1 = s ? s1[4 * rg + 1] : s0[4 * rg + 1];
        float p2 = s ? s1[4 * rg + 2] : s0[4 * rg + 2];
        float p3 = s ? s1[4 * rg + 3] : s0[4 * rg + 3];
        // keys kb4..kb4+3, kb4 = 8*rg + 4*h5 + 32*s  (C-row map, verified)
        const int g = rg + 4 * s;                 // kb4 >> 3
        const int idx = l31 * 64 + (g ^ q7) * 8 + 4 * h5;
        uint2 pw = {pk2(p0, p1), pk2(p2, p3)};
        *reinterpret_cast<uint2*>(&PsW[idx]) = pw;
      }
    }

    // ---- O^T += V^T P^T
    bf16x8 pb[4];
    #pragma unroll
    for (int tt = 0; tt < 4; tt++)
      pb[tt] = *reinterpret_cast<const bf16x8*>(
          &PsW[l31 * 64 + ((2 * tt + h5) ^ q7) * 8]);
    __builtin_amdgcn_s_setprio(1);
    #pragma unroll
    for (int tt = 0; tt < 4; tt++) {
      const int g = (2 * tt + h5);
      bf16x8 va0 = *reinterpret_cast<const bf16x8*>(
          &VtB[l31 * 64 + (g ^ q7) * 8]);
      bf16x8 va1 = *reinterpret_cast<const bf16x8*>(
          &VtB[(32 + l31) * 64 + (g ^ q7) * 8]);
      o0 = __builtin_amdgcn_mfma_f32_32x32x16_bf16(va0, pb[tt], o0, 0, 0, 0);
      o1 = __builtin_amdgcn_mfma_f32_32x32x16_bf16(va1, pb[tt], o1, 0, 0, 0);
    }
    __builtin_amdgcn_s_setprio(0);

    if (t < SEQ / 64 - 1) {
      __builtin_amdgcn_sched_barrier(0);
      __builtin_amdgcn_s_barrier();   // all waves done reading before restage
    }
  }

  // ---- epilogue: O^T regs -> ctx[q][d], lane-local q = q0 + l31
  const float rl = 1.0f / l;
  const size_t orow = base + (size_t)(q0 + l31) * EMB;
  #pragma unroll
  for (int s = 0; s < 2; s++) {
    #pragma unroll
    for (int rg = 0; rg < 4; rg++) {
      float v0 = (s ? o1[4 * rg]     : o0[4 * rg])     * rl;
      float v1 = (s ? o1[4 * rg + 1] : o0[4 * rg + 1]) * rl;
      float v2 = (s ? o1[4 * rg + 2] : o0[4 * rg + 2]) * rl;
      float v3 = (s ? o1[4 * rg + 3] : o0[4 * rg + 3]) * rl;
      const int d0 = 8 * rg + 4 * h5 + 32 * s;       // C-row map = d
      uint2 pw = {pk2(v0, v1), pk2(v2, v3)};
      *reinterpret_cast<uint2*>(&ctx[orow + d0]) = pw;
    }
  }
}

// ---------------------------------------------------------------------------
// K3: bf16 MFMA GEMM (m97 structure): out[t][c] = sum_i X[t][i]*W[c][i] + ...
// ---------------------------------------------------------------------------
template <int K, bool RELU, bool RES, bool OBF>
__global__ __launch_bounds__(256) void gemm_mfma(
    const unsigned short* __restrict__ X, const unsigned short* __restrict__ W,
    const float* __restrict__ bias, const float* __restrict__ resid,
    void* __restrict__ outp, int Nout) {
  __shared__ unsigned short As[128 * 32];
  __shared__ unsigned short Bs[128 * 32];
  const int tid = threadIdx.x;
  const int w = tid >> 6, lane = tid & 63;
  const int lg = lane >> 4, lc = lane & 15;
  const int wr = w >> 1, wc = w & 1;
  const int c0 = blockIdx.x * 128, t0 = blockIdx.y * 128;
  const int srow = lane >> 2;
  const int scol = (lane & 3) * 8;

  f32x4 acc[4][4];
  #pragma unroll
  for (int m = 0; m < 4; m++)
    #pragma unroll
    for (int n = 0; n < 4; n++) {
      f32x4 z = {0.f, 0.f, 0.f, 0.f};
      acc[m][n] = z;
    }

  for (int i0 = 0; i0 < K; i0 += 32) {
    __syncthreads();
    #pragma unroll
    for (int c = 0; c < 2; c++) {
      const int slab = w * 2 + c;
      gload_lds16(&X[(size_t)(t0 + slab * 16 + srow) * K + i0 + scol],
                  &As[slab * 512]);
      gload_lds16(&W[(size_t)(c0 + slab * 16 + srow) * K + i0 + scol],
                  &Bs[slab * 512]);
    }
    __syncthreads();
    bf16x8 a[4], b[4];
    #pragma unroll
    for (int m = 0; m < 4; m++)
      a[m] = *reinterpret_cast<const bf16x8*>(&As[(wr * 64 + m * 16 + lc) * 32 + lg * 8]);
    #pragma unroll
    for (int n = 0; n < 4; n++)
      b[n] = *reinterpret_cast<const bf16x8*>(&Bs[(wc * 64 + n * 16 + lc) * 32 + lg * 8]);
    #pragma unroll
    for (int m = 0; m < 4; m++)
      #pragma unroll
      for (int n = 0; n < 4; n++)
        acc[m][n] = __builtin_amdgcn_mfma_f32_16x16x32_bf16(a[m], b[n], acc[m][n], 0, 0, 0);
  }

  float* outf = (float*)outp;
  unsigned short* outb = (unsigned short*)outp;
  #pragma unroll
  for (int m = 0; m < 4; m++) {
    #pragma unroll
    for (int r = 0; r < 4; r++) {
      int row = t0 + wr * 64 + m * 16 + lg * 4 + r;
      #pragma unroll
      for (int n = 0; n < 4; n++) {
        int col = c0 + wc * 64 + n * 16 + lc;
        float val = acc[m][n][r] + bias[col];
        if constexpr (RES) val += resid[(size_t)row * Nout + col];
        if constexpr (RELU) val = fmaxf(val, 0.f);
        if constexpr (OBF) outb[(size_t)row * Nout + col] = f2bf(val);
        else outf[(size_t)row * Nout + col] = val;
      }
    }
  }
}

// ---------------------------------------------------------------------------
// K4: in-place LayerNorm over rows of width 1024 (+ optional bf16 copy).
// ---------------------------------------------------------------------------
__global__ __launch_bounds__(256) void ln_kernel(
    float* __restrict__ io, const float* __restrict__ g,
    const float* __restrict__ b, unsigned short* __restrict__ ob) {
  __shared__ float sw[4], ssw[4];
  const int tid = threadIdx.x;
  const int row = blockIdx.x;
  const int wave = tid >> 6, lane = tid & 63;
  float vals[4];
  float s = 0.f, ss = 0.f;
  #pragma unroll
  for (int j = 0; j < 4; j++) {
    float vv = io[(size_t)row * EMB + tid + 256 * j];
    vals[j] = vv; s += vv; ss += vv * vv;
  }
  #pragma unroll
  for (int off = 32; off >= 1; off >>= 1) {
    s += __shfl_xor(s, off, 64);
    ss += __shfl_xor(ss, off, 64);
  }
  if (lane == 0) { sw[wave] = s; ssw[wave] = ss; }
  __syncthreads();
  float st = sw[0] + sw[1] + sw[2] + sw[3];
  float sst = ssw[0] + ssw[1] + ssw[2] + ssw[3];
  float mu = st * (1.f / EMB);
  float var = sst * (1.f / EMB) - mu * mu;
  float rs = rsqrtf(var + 1e-5f);
  #pragma unroll
  for (int j = 0; j < 4; j++) {
    int e = tid + 256 * j;
    float r = (vals[j] - mu) * rs * g[e] + b[e];
    io[(size_t)row * EMB + e] = r;
    if (ob) ob[(size_t)row * EMB + e] = f2bf(r);
  }
}

// ---------------------------------------------------------------------------
extern "C" void kernel_launch(void* const* d_in, const int* in_sizes, int n_in,
                              void* d_out, int out_size, void* d_ws, size_t ws_size,
                              hipStream_t stream) {
  const float* x    = (const float*)d_in[0];
  const float* Wq   = (const float*)d_in[1];
  const float* Wk   = (const float*)d_in[2];
  const float* Wv   = (const float*)d_in[3];
  const float* Wo   = (const float*)d_in[4];
  const float* bo   = (const float*)d_in[5];
  const float* ln1g = (const float*)d_in[6];
  const float* ln1b = (const float*)d_in[7];
  const float* ln2g = (const float*)d_in[8];
  const float* ln2b = (const float*)d_in[9];
  const float* W1   = (const float*)d_in[10];
  const float* b1   = (const float*)d_in[11];
  const float* W2   = (const float*)d_in[12];
  const float* b2   = (const float*)d_in[13];
  float* out = (float*)d_out;

  const size_t TE = (size_t)TOKENS * EMB;
  const size_t MB = 1024 * 1024;
  unsigned short* qb  = (unsigned short*)d_ws;
  unsigned short* kb  = qb + TE;
  unsigned short* vb  = kb + TE;
  unsigned short* ctx = vb + TE;
  unsigned short* ff1 = (unsigned short*)d_ws;
  float*          x1  = (float*)((char*)d_ws + 32 * MB);
  unsigned short* vT  = (unsigned short*)((char*)d_ws + 32 * MB);
  unsigned short* x1b = (unsigned short*)((char*)d_ws + 48 * MB);
  unsigned short* Wob = (unsigned short*)((char*)d_ws + 56 * MB);
  unsigned short* W1b = (unsigned short*)((char*)d_ws + 58 * MB);
  unsigned short* W2b = (unsigned short*)((char*)d_ws + 66 * MB);

  cvt_kernel<<<EMB * EMB / 2048, 256, 0, stream>>>(Wo, Wob, EMB * EMB);
  cvt_kernel<<<FFN_D * EMB / 2048, 256, 0, stream>>>(W1, W1b, FFN_D * EMB);
  cvt_kernel<<<FFN_D * EMB / 2048, 256, 0, stream>>>(W2, W2b, FFN_D * EMB);

  qkv_kernel<<<1024, 256, 0, stream>>>(x, Wq, Wk, Wv, qb, kb, vb);
  vtrans_kernel<<<1024, 256, 0, stream>>>(vb, vT);
  attn_mfma<<<512, 256, 0, stream>>>(qb, kb, vT, ctx);
  gemm_mfma<1024, false, true, false>
      <<<dim3(EMB / 128, TOKENS / 128), 256, 0, stream>>>(ctx, Wob, bo, x, x1, EMB);
  ln_kernel<<<TOKENS, 256, 0, stream>>>(x1, ln1g, ln1b, x1b);
  gemm_mfma<1024, true, false, true>
      <<<dim3(FFN_D / 128, TOKENS / 128), 256, 0, stream>>>(x1b, W1b, b1, nullptr, ff1, FFN_D);
  gemm_mfma<4096, false, true, false>
      <<<dim3(EMB / 128, TOKENS / 128), 256, 0, stream>>>(ff1, W2b, b2, x1, out, EMB);
  ln_kernel<<<TOKENS, 256, 0, stream>>>(out, ln2g, ln2b, nullptr);
}

// Round 6
// 271.999 us; speedup vs baseline: 11.5947x; 1.2980x over previous
//
#include <hip/hip_runtime.h>
#include <hip/hip_bf16.h>

#define TOKENS 4096   // N*S = 2*2048
#define EMB    1024
#define SEQ    2048
#define NHEAD  16
#define HDIM   64
#define FFN_D  4096

typedef __attribute__((ext_vector_type(8))) short bf16x8;
typedef __attribute__((ext_vector_type(4))) float f32x4;
typedef __attribute__((ext_vector_type(16))) float f32x16;

static __device__ __forceinline__ unsigned short f2bf(float f) {
  unsigned int u = __float_as_uint(f);
  unsigned int r = (u + 0x7fffu + ((u >> 16) & 1u)) >> 16;  // RNE
  return (unsigned short)r;
}

static __device__ __forceinline__ unsigned int pk2(float a, float b) {
  __hip_bfloat162 h = __float22bfloat162_rn(float2{a, b});
  return *reinterpret_cast<unsigned int*>(&h);
}

// async global->LDS, 16B per lane; LDS dest = wave-uniform base + lane*16
static __device__ __forceinline__ void gload_lds16(const unsigned short* g,
                                                   unsigned short* l) {
  __builtin_amdgcn_global_load_lds(
      (const __attribute__((address_space(1))) void*)g,
      (__attribute__((address_space(3))) void*)l, 16, 0, 0);
}

// ---------------------------------------------------------------------------
// K0: f32 -> bf16 convert (weights), 8 elems/thread
// ---------------------------------------------------------------------------
__global__ __launch_bounds__(256) void cvt_kernel(
    const float* __restrict__ in, unsigned short* __restrict__ out, int n) {
  int i = (blockIdx.x * 256 + threadIdx.x) * 8;
  if (i >= n) return;
  float4 v0 = *reinterpret_cast<const float4*>(&in[i]);
  float4 v1 = *reinterpret_cast<const float4*>(&in[i + 4]);
  bf16x8 ov;
  ov[0] = (short)f2bf(v0.x); ov[1] = (short)f2bf(v0.y);
  ov[2] = (short)f2bf(v0.z); ov[3] = (short)f2bf(v0.w);
  ov[4] = (short)f2bf(v1.x); ov[5] = (short)f2bf(v1.y);
  ov[6] = (short)f2bf(v1.z); ov[7] = (short)f2bf(v1.w);
  *reinterpret_cast<bf16x8*>(&out[i]) = ov;
}

// ---------------------------------------------------------------------------
// K1: MFMA QKV projection. Block = 64 tokens x 1 head, 4 waves (16 tok each).
// q,k swapped-operand (D rows = e, 4 consecutive per lane -> 8B row stores);
// v normal (D rows = t -> 8B stores straight into transposed vT layout).
// ---------------------------------------------------------------------------
__global__ __launch_bounds__(256) void qkv_mfma(
    const float* __restrict__ x,
    const float* __restrict__ Wq, const float* __restrict__ Wk,
    const float* __restrict__ Wv,
    unsigned short* __restrict__ q, unsigned short* __restrict__ k,
    unsigned short* __restrict__ vT) {
  __shared__ unsigned short Xs[64][72];
  __shared__ unsigned short Wqs[64][72], Wks[64][72], Wvs[64][72];
  const int tid = threadIdx.x;
  const int w = tid >> 6, lane = tid & 63;
  const int lg = lane >> 4, lc = lane & 15;
  const int b = blockIdx.x;
  const int T0 = (b >> 4) * 64;
  const int h = b & 15;
  const int n = T0 >> 11;             // token tile never straddles batch (64|2048)
  const int s0 = T0 & 2047;

  // stage x slice [64 t][64 d] -> bf16 LDS
  #pragma unroll
  for (int it = 0; it < 4; it++) {
    int idx = it * 256 + tid;
    int row = idx >> 4, c4 = (idx & 15) * 4;
    float4 xv = *reinterpret_cast<const float4*>(
        &x[(size_t)(T0 + row) * EMB + h * 64 + c4]);
    uint2 pw = {pk2(xv.x, xv.y), pk2(xv.z, xv.w)};
    *reinterpret_cast<uint2*>(&Xs[row][c4]) = pw;
  }
  // stage weights [64 e][64 d] -> bf16 LDS (x3)
  #pragma unroll
  for (int it = 0; it < 4; it++) {
    int idx = it * 256 + tid;
    int e = idx >> 4, c4 = (idx & 15) * 4;
    float4 a = *reinterpret_cast<const float4*>(&Wq[e * 64 + c4]);
    float4 c = *reinterpret_cast<const float4*>(&Wk[e * 64 + c4]);
    float4 d = *reinterpret_cast<const float4*>(&Wv[e * 64 + c4]);
    uint2 pa = {pk2(a.x, a.y), pk2(a.z, a.w)};
    uint2 pc = {pk2(c.x, c.y), pk2(c.z, c.w)};
    uint2 pd = {pk2(d.x, d.y), pk2(d.z, d.w)};
    *reinterpret_cast<uint2*>(&Wqs[e][c4]) = pa;
    *reinterpret_cast<uint2*>(&Wks[e][c4]) = pc;
    *reinterpret_cast<uint2*>(&Wvs[e][c4]) = pd;
  }
  __syncthreads();

  // x fragment for this wave's 16 tokens (used as B for q/k, as A for v)
  bf16x8 xf0 = *reinterpret_cast<const bf16x8*>(&Xs[w * 16 + lc][lg * 8]);
  bf16x8 xf1 = *reinterpret_cast<const bf16x8*>(&Xs[w * 16 + lc][32 + lg * 8]);

  f32x4 aq[4], ak[4], av[4];
  #pragma unroll
  for (int eg = 0; eg < 4; eg++) {
    f32x4 z = {0.f, 0.f, 0.f, 0.f};
    aq[eg] = z; ak[eg] = z; av[eg] = z;
  }

  #pragma unroll
  for (int eg = 0; eg < 4; eg++) {
    bf16x8 wq0 = *reinterpret_cast<const bf16x8*>(&Wqs[eg * 16 + lc][lg * 8]);
    bf16x8 wq1 = *reinterpret_cast<const bf16x8*>(&Wqs[eg * 16 + lc][32 + lg * 8]);
    bf16x8 wk0 = *reinterpret_cast<const bf16x8*>(&Wks[eg * 16 + lc][lg * 8]);
    bf16x8 wk1 = *reinterpret_cast<const bf16x8*>(&Wks[eg * 16 + lc][32 + lg * 8]);
    bf16x8 wv0 = *reinterpret_cast<const bf16x8*>(&Wvs[eg * 16 + lc][lg * 8]);
    bf16x8 wv1 = *reinterpret_cast<const bf16x8*>(&Wvs[eg * 16 + lc][32 + lg * 8]);
    aq[eg] = __builtin_amdgcn_mfma_f32_16x16x32_bf16(wq0, xf0, aq[eg], 0, 0, 0);
    aq[eg] = __builtin_amdgcn_mfma_f32_16x16x32_bf16(wq1, xf1, aq[eg], 0, 0, 0);
    ak[eg] = __builtin_amdgcn_mfma_f32_16x16x32_bf16(wk0, xf0, ak[eg], 0, 0, 0);
    ak[eg] = __builtin_amdgcn_mfma_f32_16x16x32_bf16(wk1, xf1, ak[eg], 0, 0, 0);
    av[eg] = __builtin_amdgcn_mfma_f32_16x16x32_bf16(xf0, wv0, av[eg], 0, 0, 0);
    av[eg] = __builtin_amdgcn_mfma_f32_16x16x32_bf16(xf1, wv1, av[eg], 0, 0, 0);
  }

  // q,k: D[e][t] -> e = eg*16 + lg*4 + r, t = w*16 + lc  (8B row stores)
  const size_t qoff = (size_t)(T0 + w * 16 + lc) * EMB + h * 64;
  #pragma unroll
  for (int eg = 0; eg < 4; eg++) {
    uint2 pq = {pk2(aq[eg][0], aq[eg][1]), pk2(aq[eg][2], aq[eg][3])};
    uint2 pk = {pk2(ak[eg][0], ak[eg][1]), pk2(ak[eg][2], ak[eg][3])};
    *reinterpret_cast<uint2*>(&q[qoff + eg * 16 + lg * 4]) = pq;
    *reinterpret_cast<uint2*>(&k[qoff + eg * 16 + lg * 4]) = pk;
  }
  // v: D[t][e] -> t = w*16 + lg*4 + r, e = eg*16 + lc; store to vT[n][h][e][s]
  const size_t vtb = (size_t)(n * 16 + h) * 64 * SEQ;
  #pragma unroll
  for (int eg = 0; eg < 4; eg++) {
    uint2 pv = {pk2(av[eg][0], av[eg][1]), pk2(av[eg][2], av[eg][3])};
    *reinterpret_cast<uint2*>(
        &vT[vtb + (size_t)(eg * 16 + lc) * SEQ + s0 + w * 16 + lg * 4]) = pv;
  }
}

// ---------------------------------------------------------------------------
// K2: MFMA flash attention, swapped-operand 32x32x16 design.
// ---------------------------------------------------------------------------
__global__ __launch_bounds__(256) void attn_mfma(
    const unsigned short* __restrict__ qg, const unsigned short* __restrict__ kg,
    const unsigned short* __restrict__ vtg, unsigned short* __restrict__ ctx) {
  __shared__ unsigned short Ks[2][4096];   // [64 key][8 granules of 8 dims]
  __shared__ unsigned short Vt[2][4096];   // [64 dim][8 granules of 8 keys]
  __shared__ unsigned short Ps[4][2048];   // per wave: [32 q][8 granules of 8 keys]
  const int tid = threadIdx.x;
  const int w = tid >> 6, lane = tid & 63;
  const int l31 = lane & 31, h5 = lane >> 5;
  const int q7 = l31 & 7;
  const int b = blockIdx.x;
  const int qt = b & 15, nh = b >> 4;
  const int n = nh >> 4, h = nh & 15;
  const size_t base = (size_t)n * SEQ * EMB + h * 64;
  const size_t vtbase = (size_t)(n * 16 + h) * 64 * SEQ;
  const int q0 = qt * 128 + w * 32;

  bf16x8 qa[4];
  #pragma unroll
  for (int t = 0; t < 4; t++)
    qa[t] = *reinterpret_cast<const bf16x8*>(
        &qg[base + (size_t)(q0 + l31) * EMB + 16 * t + 8 * h5]);

  f32x16 o0 = {}, o1 = {};
  float m = -1e30f, l = 0.f;

  auto stage = [&](int bi, int t) {
    const int j0 = t * 64;
    #pragma unroll
    for (int rnd = 0; rnd < 2; rnd++) {
      const int glbase = rnd * 256 + w * 64;
      const int gl = glbase + lane;
      const int row = gl >> 3, gp = gl & 7;
      const int gsrc = (gp ^ (row & 7)) * 8;
      gload_lds16(&kg[base + (size_t)(j0 + row) * EMB + gsrc], &Ks[bi][glbase * 8]);
      gload_lds16(&vtg[vtbase + (size_t)row * SEQ + j0 + gsrc], &Vt[bi][glbase * 8]);
    }
  };

  stage(0, 0);
  #pragma unroll 1
  for (int t = 0; t < SEQ / 64; ++t) {
    if (t < SEQ / 64 - 1) {
      stage((t + 1) & 1, t + 1);
      asm volatile("s_waitcnt vmcnt(4)" ::: "memory");
    } else {
      asm volatile("s_waitcnt vmcnt(0)" ::: "memory");
    }
    __builtin_amdgcn_sched_barrier(0);
    __builtin_amdgcn_s_barrier();
    __builtin_amdgcn_sched_barrier(0);

    const unsigned short* KsB = &Ks[t & 1][0];
    const unsigned short* VtB = &Vt[t & 1][0];
    unsigned short* PsW = &Ps[w][0];

    f32x16 s0 = {}, s1 = {};
    __builtin_amdgcn_s_setprio(1);
    #pragma unroll
    for (int tt = 0; tt < 4; tt++) {
      const int g = (2 * tt + h5);
      bf16x8 ka0 = *reinterpret_cast<const bf16x8*>(
          &KsB[l31 * 64 + (g ^ q7) * 8]);
      bf16x8 ka1 = *reinterpret_cast<const bf16x8*>(
          &KsB[(32 + l31) * 64 + (g ^ q7) * 8]);
      s0 = __builtin_amdgcn_mfma_f32_32x32x16_bf16(ka0, qa[tt], s0, 0, 0, 0);
      s1 = __builtin_amdgcn_mfma_f32_32x32x16_bf16(ka1, qa[tt], s1, 0, 0, 0);
    }
    __builtin_amdgcn_s_setprio(0);

    #pragma unroll
    for (int r = 0; r < 16; r++) { s0[r] *= 0.03125f; s1[r] *= 0.03125f; }
    float tm = -1e30f;
    #pragma unroll
    for (int r = 0; r < 16; r++) tm = fmaxf(tm, fmaxf(s0[r], s1[r]));
    tm = fmaxf(tm, __shfl_xor(tm, 32));
    const float mn = fmaxf(m, tm);
    const float sc = __expf(m - mn);
    m = mn;
    float ps = 0.f;
    #pragma unroll
    for (int r = 0; r < 16; r++) {
      s0[r] = __expf(s0[r] - mn); ps += s0[r];
      s1[r] = __expf(s1[r] - mn); ps += s1[r];
    }
    ps += __shfl_xor(ps, 32);
    l = l * sc + ps;
    #pragma unroll
    for (int r = 0; r < 16; r++) { o0[r] *= sc; o1[r] *= sc; }

    #pragma unroll
    for (int s = 0; s < 2; s++) {
      #pragma unroll
      for (int rg = 0; rg < 4; rg++) {
        float p0 = s ? s1[4 * rg] : s0[4 * rg];
        float p1 = s ? s1[4 * rg + 1] : s0[4 * rg + 1];
        float p2 = s ? s1[4 * rg + 2] : s0[4 * rg + 2];
        float p3 = s ? s1[4 * rg + 3] : s0[4 * rg + 3];
        const int g = rg + 4 * s;
        const int idx = l31 * 64 + (g ^ q7) * 8 + 4 * h5;
        uint2 pw = {pk2(p0, p1), pk2(p2, p3)};
        *reinterpret_cast<uint2*>(&PsW[idx]) = pw;
      }
    }

    bf16x8 pb[4];
    #pragma unroll
    for (int tt = 0; tt < 4; tt++)
      pb[tt] = *reinterpret_cast<const bf16x8*>(
          &PsW[l31 * 64 + ((2 * tt + h5) ^ q7) * 8]);
    __builtin_amdgcn_s_setprio(1);
    #pragma unroll
    for (int tt = 0; tt < 4; tt++) {
      const int g = (2 * tt + h5);
      bf16x8 va0 = *reinterpret_cast<const bf16x8*>(
          &VtB[l31 * 64 + (g ^ q7) * 8]);
      bf16x8 va1 = *reinterpret_cast<const bf16x8*>(
          &VtB[(32 + l31) * 64 + (g ^ q7) * 8]);
      o0 = __builtin_amdgcn_mfma_f32_32x32x16_bf16(va0, pb[tt], o0, 0, 0, 0);
      o1 = __builtin_amdgcn_mfma_f32_32x32x16_bf16(va1, pb[tt], o1, 0, 0, 0);
    }
    __builtin_amdgcn_s_setprio(0);

    if (t < SEQ / 64 - 1) {
      __builtin_amdgcn_sched_barrier(0);
      __builtin_amdgcn_s_barrier();
    }
  }

  const float rl = 1.0f / l;
  const size_t orow = base + (size_t)(q0 + l31) * EMB;
  #pragma unroll
  for (int s = 0; s < 2; s++) {
    #pragma unroll
    for (int rg = 0; rg < 4; rg++) {
      float v0 = (s ? o1[4 * rg]     : o0[4 * rg])     * rl;
      float v1 = (s ? o1[4 * rg + 1] : o0[4 * rg + 1]) * rl;
      float v2 = (s ? o1[4 * rg + 2] : o0[4 * rg + 2]) * rl;
      float v3 = (s ? o1[4 * rg + 3] : o0[4 * rg + 3]) * rl;
      const int d0 = 8 * rg + 4 * h5 + 32 * s;
      uint2 pw = {pk2(v0, v1), pk2(v2, v3)};
      *reinterpret_cast<uint2*>(&ctx[orow + d0]) = pw;
    }
  }
}

// ---------------------------------------------------------------------------
// K3: bf16 MFMA GEMM (m97 structure): out[t][c] = sum_i X[t][i]*W[c][i] + ...
// ---------------------------------------------------------------------------
template <int K, bool RELU, bool RES, bool OBF>
__global__ __launch_bounds__(256) void gemm_mfma(
    const unsigned short* __restrict__ X, const unsigned short* __restrict__ W,
    const float* __restrict__ bias, const float* __restrict__ resid,
    void* __restrict__ outp, int Nout) {
  __shared__ unsigned short As[128 * 32];
  __shared__ unsigned short Bs[128 * 32];
  const int tid = threadIdx.x;
  const int w = tid >> 6, lane = tid & 63;
  const int lg = lane >> 4, lc = lane & 15;
  const int wr = w >> 1, wc = w & 1;
  const int c0 = blockIdx.x * 128, t0 = blockIdx.y * 128;
  const int srow = lane >> 2;
  const int scol = (lane & 3) * 8;

  f32x4 acc[4][4];
  #pragma unroll
  for (int m = 0; m < 4; m++)
    #pragma unroll
    for (int n = 0; n < 4; n++) {
      f32x4 z = {0.f, 0.f, 0.f, 0.f};
      acc[m][n] = z;
    }

  for (int i0 = 0; i0 < K; i0 += 32) {
    __syncthreads();
    #pragma unroll
    for (int c = 0; c < 2; c++) {
      const int slab = w * 2 + c;
      gload_lds16(&X[(size_t)(t0 + slab * 16 + srow) * K + i0 + scol],
                  &As[slab * 512]);
      gload_lds16(&W[(size_t)(c0 + slab * 16 + srow) * K + i0 + scol],
                  &Bs[slab * 512]);
    }
    __syncthreads();
    bf16x8 a[4], b[4];
    #pragma unroll
    for (int m = 0; m < 4; m++)
      a[m] = *reinterpret_cast<const bf16x8*>(&As[(wr * 64 + m * 16 + lc) * 32 + lg * 8]);
    #pragma unroll
    for (int n = 0; n < 4; n++)
      b[n] = *reinterpret_cast<const bf16x8*>(&Bs[(wc * 64 + n * 16 + lc) * 32 + lg * 8]);
    #pragma unroll
    for (int m = 0; m < 4; m++)
      #pragma unroll
      for (int n = 0; n < 4; n++)
        acc[m][n] = __builtin_amdgcn_mfma_f32_16x16x32_bf16(a[m], b[n], acc[m][n], 0, 0, 0);
  }

  float* outf = (float*)outp;
  unsigned short* outb = (unsigned short*)outp;
  #pragma unroll
  for (int m = 0; m < 4; m++) {
    #pragma unroll
    for (int r = 0; r < 4; r++) {
      int row = t0 + wr * 64 + m * 16 + lg * 4 + r;
      #pragma unroll
      for (int n = 0; n < 4; n++) {
        int col = c0 + wc * 64 + n * 16 + lc;
        float val = acc[m][n][r] + bias[col];
        if constexpr (RES) val += resid[(size_t)row * Nout + col];
        if constexpr (RELU) val = fmaxf(val, 0.f);
        if constexpr (OBF) outb[(size_t)row * Nout + col] = f2bf(val);
        else outf[(size_t)row * Nout + col] = val;
      }
    }
  }
}

// ---------------------------------------------------------------------------
// K4: in-place LayerNorm over rows of width 1024 (+ optional bf16 copy).
// ---------------------------------------------------------------------------
__global__ __launch_bounds__(256) void ln_kernel(
    float* __restrict__ io, const float* __restrict__ g,
    const float* __restrict__ b, unsigned short* __restrict__ ob) {
  __shared__ float sw[4], ssw[4];
  const int tid = threadIdx.x;
  const int row = blockIdx.x;
  const int wave = tid >> 6, lane = tid & 63;
  float vals[4];
  float s = 0.f, ss = 0.f;
  #pragma unroll
  for (int j = 0; j < 4; j++) {
    float vv = io[(size_t)row * EMB + tid + 256 * j];
    vals[j] = vv; s += vv; ss += vv * vv;
  }
  #pragma unroll
  for (int off = 32; off >= 1; off >>= 1) {
    s += __shfl_xor(s, off, 64);
    ss += __shfl_xor(ss, off, 64);
  }
  if (lane == 0) { sw[wave] = s; ssw[wave] = ss; }
  __syncthreads();
  float st = sw[0] + sw[1] + sw[2] + sw[3];
  float sst = ssw[0] + ssw[1] + ssw[2] + ssw[3];
  float mu = st * (1.f / EMB);
  float var = sst * (1.f / EMB) - mu * mu;
  float rs = rsqrtf(var + 1e-5f);
  #pragma unroll
  for (int j = 0; j < 4; j++) {
    int e = tid + 256 * j;
    float r = (vals[j] - mu) * rs * g[e] + b[e];
    io[(size_t)row * EMB + e] = r;
    if (ob) ob[(size_t)row * EMB + e] = f2bf(r);
  }
}

// ---------------------------------------------------------------------------
extern "C" void kernel_launch(void* const* d_in, const int* in_sizes, int n_in,
                              void* d_out, int out_size, void* d_ws, size_t ws_size,
                              hipStream_t stream) {
  const float* x    = (const float*)d_in[0];
  const float* Wq   = (const float*)d_in[1];
  const float* Wk   = (const float*)d_in[2];
  const float* Wv   = (const float*)d_in[3];
  const float* Wo   = (const float*)d_in[4];
  const float* bo   = (const float*)d_in[5];
  const float* ln1g = (const float*)d_in[6];
  const float* ln1b = (const float*)d_in[7];
  const float* ln2g = (const float*)d_in[8];
  const float* ln2b = (const float*)d_in[9];
  const float* W1   = (const float*)d_in[10];
  const float* b1   = (const float*)d_in[11];
  const float* W2   = (const float*)d_in[12];
  const float* b2   = (const float*)d_in[13];
  float* out = (float*)d_out;

  const size_t TE = (size_t)TOKENS * EMB;
  const size_t MB = 1024 * 1024;
  // [0,8)MB qb | [8,16) kb | [16,24) vT | [24,32) ctx  (bf16)
  unsigned short* qb  = (unsigned short*)d_ws;
  unsigned short* kb  = qb + TE;
  unsigned short* vT  = kb + TE;
  unsigned short* ctx = vT + TE;
  // ff1 bf16 [0,32)MB — reuses qb..ctx after attention+Wo-gemm consumed them
  unsigned short* ff1 = (unsigned short*)d_ws;
  float*          x1  = (float*)((char*)d_ws + 32 * MB);
  unsigned short* x1b = (unsigned short*)((char*)d_ws + 48 * MB);
  unsigned short* Wob = (unsigned short*)((char*)d_ws + 56 * MB);
  unsigned short* W1b = (unsigned short*)((char*)d_ws + 58 * MB);
  unsigned short* W2b = (unsigned short*)((char*)d_ws + 66 * MB);

  cvt_kernel<<<EMB * EMB / 2048, 256, 0, stream>>>(Wo, Wob, EMB * EMB);
  cvt_kernel<<<FFN_D * EMB / 2048, 256, 0, stream>>>(W1, W1b, FFN_D * EMB);
  cvt_kernel<<<FFN_D * EMB / 2048, 256, 0, stream>>>(W2, W2b, FFN_D * EMB);

  qkv_mfma<<<(TOKENS / 64) * NHEAD, 256, 0, stream>>>(x, Wq, Wk, Wv, qb, kb, vT);
  attn_mfma<<<512, 256, 0, stream>>>(qb, kb, vT, ctx);
  gemm_mfma<1024, false, true, false>
      <<<dim3(EMB / 128, TOKENS / 128), 256, 0, stream>>>(ctx, Wob, bo, x, x1, EMB);
  ln_kernel<<<TOKENS, 256, 0, stream>>>(x1, ln1g, ln1b, x1b);
  gemm_mfma<1024, true, false, true>
      <<<dim3(FFN_D / 128, TOKENS / 128), 256, 0, stream>>>(x1b, W1b, b1, nullptr, ff1, FFN_D);
  gemm_mfma<4096, false, true, false>
      <<<dim3(EMB / 128, TOKENS / 128), 256, 0, stream>>>(ff1, W2b, b2, x1, out, EMB);
  ln_kernel<<<TOKENS, 256, 0, stream>>>(out, ln2g, ln2b, nullptr);
}